// Round 1
// baseline (121.429 us; speedup 1.0000x reference)
//
#include <hip/hip_runtime.h>
#include <stdint.h>

typedef unsigned short u16;
typedef __attribute__((ext_vector_type(8))) short short8;
typedef __attribute__((ext_vector_type(4))) float f32x4;

#define BATCH 4
#define SEQ   2048
#define DIN   768
#define DK    128
#define DV    768
#define MTOT  (BATCH*SEQ)   // 8192
#define NQKV  1024          // 128 q + 128 k + 768 v

__device__ __forceinline__ u16 f2bf(float f) {
  union { float f; uint32_t u; } v; v.f = f;
  uint32_t r = v.u + 0x7FFFu + ((v.u >> 16) & 1u);
  return (u16)(r >> 16);
}
__device__ __forceinline__ float bf2f(u16 h) {
  union { uint32_t u; float f; } v; v.u = ((uint32_t)h) << 16;
  return v.f;
}

// ---------------- K0a: pack weights (transposed, bf16) + bias ----------------
__global__ void pack_weights(const float* __restrict__ Wq, const float* __restrict__ bq,
                             const float* __restrict__ Wk, const float* __restrict__ bk,
                             const float* __restrict__ Wv, const float* __restrict__ bv,
                             u16* __restrict__ WbT, float* __restrict__ biasP) {
  int n = blockIdx.x;  // 0..1023 output column
  if (threadIdx.x == 0) {
    float b = (n < DK) ? bq[n] : (n < 2*DK ? bk[n - DK] : bv[n - 2*DK]);
    biasP[n] = b;
  }
  const float* col; int cn, ldw;
  if (n < DK)        { col = Wq; cn = n;        ldw = DK; }
  else if (n < 2*DK) { col = Wk; cn = n - DK;   ldw = DK; }
  else               { col = Wv; cn = n - 2*DK; ldw = DV; }
  for (int i = threadIdx.x; i < DIN; i += blockDim.x) {
    WbT[(size_t)n * DIN + i] = f2bf(col[(size_t)i * ldw + cn]);
  }
}

// ---------------- K0b: convert x fp32 -> bf16 ----------------
__global__ void convert_x(const float* __restrict__ x, u16* __restrict__ xb) {
  int i = (blockIdx.x * blockDim.x + threadIdx.x) * 4;
  float4 v = *(const float4*)(x + i);
  u16 o[4] = { f2bf(v.x), f2bf(v.y), f2bf(v.z), f2bf(v.w) };
  *(uint2*)(xb + i) = *(const uint2*)o;
}

// ---------------- GEMM C = A * BT^T (NT form), bf16 in, 128x128 tile ----------------
// A: [M][K] row-major bf16 (lda elems), BT: [N][K] row-major bf16 (ldb elems)
// C: [M][N] (ldc elems), bf16 or f32; val = acc*alpha + bias[col]
template<bool OUT_BF16, bool HAS_BIAS>
__global__ __launch_bounds__(256, 2) void gemm_nt(
    const u16* __restrict__ A, int lda, long long sA,
    const u16* __restrict__ BT, int ldb, long long sB,
    void* __restrict__ Cv, int ldc, long long sC,
    int K, float alpha, const float* __restrict__ bias)
{
  __shared__ u16 As[128][64];
  __shared__ u16 Bs[128][64];
  const int tid = threadIdx.x;
  const int l   = tid & 63;
  const int wid = tid >> 6;
  const int wm  = wid >> 1, wn = wid & 1;
  const int m0  = blockIdx.x * 128;
  const int n0  = blockIdx.y * 128;
  const int z   = blockIdx.z;
  A  += (size_t)z * (size_t)sA;
  BT += (size_t)z * (size_t)sB;

  f32x4 acc[4][4] = {};

  const int lr = l >> 3;        // row within 8-row chunk
  const int lc = (l & 7) * 8;   // col element

  for (int k0 = 0; k0 < K; k0 += 64) {
#pragma unroll
    for (int i = 0; i < 4; ++i) {
      int c = wid * 4 + i;              // chunk 0..15, wave-uniform
      int r = c * 8 + lr;
      const u16* srcA = A + (size_t)(m0 + r) * lda + k0 + lc;
      __builtin_amdgcn_global_load_lds(
          (const __attribute__((address_space(1))) unsigned int*)srcA,
          (__attribute__((address_space(3))) unsigned int*)&As[c * 8][0],
          16, 0, 0);
      const u16* srcB = BT + (size_t)(n0 + r) * ldb + k0 + lc;
      __builtin_amdgcn_global_load_lds(
          (const __attribute__((address_space(1))) unsigned int*)srcB,
          (__attribute__((address_space(3))) unsigned int*)&Bs[c * 8][0],
          16, 0, 0);
    }
    __syncthreads();
#pragma unroll
    for (int ks = 0; ks < 2; ++ks) {
      short8 af[4], bfr[4];
#pragma unroll
      for (int i = 0; i < 4; ++i)
        af[i] = *(const short8*)&As[wm * 64 + i * 16 + (l & 15)][ks * 32 + (l >> 4) * 8];
#pragma unroll
      for (int j = 0; j < 4; ++j)
        bfr[j] = *(const short8*)&Bs[wn * 64 + j * 16 + (l & 15)][ks * 32 + (l >> 4) * 8];
#pragma unroll
      for (int i = 0; i < 4; ++i)
#pragma unroll
        for (int j = 0; j < 4; ++j)
          acc[i][j] = __builtin_amdgcn_mfma_f32_16x16x32_bf16(af[i], bfr[j], acc[i][j], 0, 0, 0);
    }
    __syncthreads();
  }

  const int rbase = (l >> 4) * 4;
  const int cl    = l & 15;
#pragma unroll
  for (int i = 0; i < 4; ++i) {
#pragma unroll
    for (int j = 0; j < 4; ++j) {
      int col = n0 + wn * 64 + j * 16 + cl;
      float bv_ = HAS_BIAS ? bias[col] : 0.0f;
#pragma unroll
      for (int q = 0; q < 4; ++q) {
        int row = m0 + wm * 64 + i * 16 + rbase + q;
        float v = acc[i][j][q] * alpha + bv_;
        if (OUT_BF16)
          ((u16*)Cv)[(size_t)z * (size_t)sC + (size_t)row * ldc + col] = f2bf(v);
        else
          ((float*)Cv)[(size_t)z * (size_t)sC + (size_t)row * ldc + col] = v;
      }
    }
  }
}

// ---------------- K2: transpose V (from qkv cols [256,1024)) -> vT[b][j][t] ----------------
__global__ void transpose_v(const u16* __restrict__ qkv, u16* __restrict__ vT) {
  __shared__ u16 tile[64][72];
  int b  = blockIdx.z;
  int t0 = blockIdx.x * 64;
  int j0 = blockIdx.y * 64;
  int tid = threadIdx.x;
  int tr = tid >> 2;          // 0..63
  int tc = (tid & 3) * 16;    // 0,16,32,48
  const u16* src = qkv + (size_t)(b * SEQ + t0 + tr) * NQKV + 2 * DK + j0 + tc;
  uint4 v0 = *(const uint4*)src;
  uint4 v1 = *(const uint4*)(src + 8);
  *(uint4*)&tile[tr][tc]     = v0;
  *(uint4*)&tile[tr][tc + 8] = v1;
  __syncthreads();
  u16 tmp[16];
#pragma unroll
  for (int u = 0; u < 16; ++u) tmp[u] = tile[tc + u][tr];
  u16* dst = vT + ((size_t)b * DV + j0 + tr) * SEQ + t0 + tc;
  *(uint4*)dst       = *(const uint4*)&tmp[0];
  *(uint4*)(dst + 8) = *(const uint4*)&tmp[8];
}

// ---------------- K4: row softmax in-place on S (bf16), one wave per row ----------------
__global__ __launch_bounds__(256) void softmax_rows(u16* __restrict__ S) {
  int row = blockIdx.x * 4 + (threadIdx.x >> 6);
  int l   = threadIdx.x & 63;
  u16* p = S + (size_t)row * SEQ;
  uint4 d[4];
#pragma unroll
  for (int c = 0; c < 4; ++c) d[c] = *(const uint4*)(p + l * 8 + c * 512);
  float v[32];
  float mx = -1e30f;
#pragma unroll
  for (int c = 0; c < 4; ++c) {
    const u16* u = (const u16*)&d[c];
#pragma unroll
    for (int e = 0; e < 8; ++e) { float f = bf2f(u[e]); v[c * 8 + e] = f; mx = fmaxf(mx, f); }
  }
#pragma unroll
  for (int s = 32; s; s >>= 1) mx = fmaxf(mx, __shfl_xor(mx, s, 64));
  float sum = 0.0f;
#pragma unroll
  for (int e = 0; e < 32; ++e) { float ex = __expf(v[e] - mx); v[e] = ex; sum += ex; }
#pragma unroll
  for (int s = 32; s; s >>= 1) sum += __shfl_xor(sum, s, 64);
  float inv = 1.0f / sum;
#pragma unroll
  for (int c = 0; c < 4; ++c) {
    u16 o[8];
#pragma unroll
    for (int e = 0; e < 8; ++e) o[e] = f2bf(v[c * 8 + e] * inv);
    *(uint4*)(p + l * 8 + c * 512) = *(const uint4*)o;
  }
}

extern "C" void kernel_launch(void* const* d_in, const int* in_sizes, int n_in,
                              void* d_out, int out_size, void* d_ws, size_t ws_size,
                              hipStream_t stream) {
  const float* x  = (const float*)d_in[0];
  const float* Wq = (const float*)d_in[1];
  const float* bq = (const float*)d_in[2];
  const float* Wk = (const float*)d_in[3];
  const float* bk = (const float*)d_in[4];
  const float* Wv = (const float*)d_in[5];
  const float* bv = (const float*)d_in[6];
  float* out = (float*)d_out;

  size_t off = 0;
  auto alloc = [&](size_t bytes) -> void* {
    void* p = (char*)d_ws + off;
    off += (bytes + 255) & ~(size_t)255;
    return p;
  };
  u16*   xb    = (u16*)alloc((size_t)MTOT * DIN * 2);      // 12.6 MB
  u16*   WbT   = (u16*)alloc((size_t)NQKV * DIN * 2);      //  1.6 MB
  float* biasP = (float*)alloc(NQKV * 4);
  u16*   qkv   = (u16*)alloc((size_t)MTOT * NQKV * 2);     // 16.8 MB
  u16*   vT    = (u16*)alloc((size_t)BATCH * DV * SEQ * 2);// 12.6 MB
  u16*   S     = (u16*)alloc((size_t)BATCH * SEQ * SEQ * 2);// 33.6 MB
  if (off > ws_size) return;  // workspace too small — fail loudly via validation

  pack_weights<<<dim3(NQKV), dim3(256), 0, stream>>>(Wq, bq, Wk, bk, Wv, bv, WbT, biasP);
  convert_x<<<dim3((MTOT * DIN / 4) / 256), dim3(256), 0, stream>>>(x, xb);

  // qkv = xb @ WbT^T + bias  (M=8192, N=1024, K=768)
  gemm_nt<true, true><<<dim3(MTOT / 128, NQKV / 128, 1), dim3(256), 0, stream>>>(
      xb, DIN, 0, WbT, DIN, 0, qkv, NQKV, 0, DIN, 1.0f, biasP);

  transpose_v<<<dim3(SEQ / 64, DV / 64, BATCH), dim3(256), 0, stream>>>(qkv, vT);

  // S = q @ k^T * (1/sqrt(128)) per batch  (M=N=2048, K=128)
  gemm_nt<true, false><<<dim3(SEQ / 128, SEQ / 128, BATCH), dim3(256), 0, stream>>>(
      qkv, NQKV, (long long)SEQ * NQKV,
      qkv + DK, NQKV, (long long)SEQ * NQKV,
      S, SEQ, (long long)SEQ * SEQ, DK, 0.088388347648318447f, nullptr);

  softmax_rows<<<dim3(MTOT / 4), dim3(256), 0, stream>>>(S);

  // out = P @ vT^T per batch  (M=2048, N=768, K=2048), fp32 out
  gemm_nt<false, false><<<dim3(SEQ / 128, DV / 128, BATCH), dim3(256), 0, stream>>>(
      S, SEQ, (long long)SEQ * SEQ,
      vT, SEQ, (long long)DV * SEQ,
      out, DV, (long long)SEQ * DV, SEQ, 1.0f, nullptr);
}

// Round 2
// 106.662 us; speedup vs baseline: 1.1384x; 1.1384x over previous
//
#include <hip/hip_runtime.h>
#include <stdint.h>

typedef unsigned short u16;
typedef __attribute__((ext_vector_type(8))) short short8;
typedef __attribute__((ext_vector_type(4))) float f32x4;

#define BATCH 4
#define SEQ   2048
#define DIN   768
#define DK    128
#define DV    768
#define MTOT  (BATCH*SEQ)   // 8192
#define NQKV  1024          // 128 q + 128 k + 768 v

__device__ __forceinline__ u16 f2bf(float f) {
  union { float f; uint32_t u; } v; v.f = f;
  uint32_t r = v.u + 0x7FFFu + ((v.u >> 16) & 1u);
  return (u16)(r >> 16);
}
__device__ __forceinline__ float bf2f(u16 h) {
  union { uint32_t u; float f; } v; v.u = ((uint32_t)h) << 16;
  return v.f;
}

// ---------------- K0a: pack weights (transposed, bf16) + bias ----------------
// 1/sqrt(DK) is folded into Wq/bq so the S-GEMM needs no alpha.
__global__ void pack_weights(const float* __restrict__ Wq, const float* __restrict__ bq,
                             const float* __restrict__ Wk, const float* __restrict__ bk,
                             const float* __restrict__ Wv, const float* __restrict__ bv,
                             u16* __restrict__ WbT, float* __restrict__ biasP) {
  const float qs = 0.088388347648318447f;  // 1/sqrt(128)
  int n = blockIdx.x;  // 0..1023 output column
  if (threadIdx.x == 0) {
    float b = (n < DK) ? bq[n] * qs : (n < 2*DK ? bk[n - DK] : bv[n - 2*DK]);
    biasP[n] = b;
  }
  const float* col; int cn, ldw; float sc;
  if (n < DK)        { col = Wq; cn = n;        ldw = DK; sc = qs;   }
  else if (n < 2*DK) { col = Wk; cn = n - DK;   ldw = DK; sc = 1.0f; }
  else               { col = Wv; cn = n - 2*DK; ldw = DV; sc = 1.0f; }
  for (int i = threadIdx.x; i < DIN; i += blockDim.x) {
    WbT[(size_t)n * DIN + i] = f2bf(col[(size_t)i * ldw + cn] * sc);
  }
}

// ---------------- K0b: convert x fp32 -> bf16 ----------------
__global__ void convert_x(const float* __restrict__ x, u16* __restrict__ xb) {
  int i = (blockIdx.x * blockDim.x + threadIdx.x) * 4;
  float4 v = *(const float4*)(x + i);
  u16 o[4] = { f2bf(v.x), f2bf(v.y), f2bf(v.z), f2bf(v.w) };
  *(uint2*)(xb + i) = *(const uint2*)o;
}

// ---------------- GEMM C = A * BT^T (NT), bf16 in, 128x128 tile, 8 waves ----------------
// A: [M][K] bf16 (lda), BT: [N][K] bf16 (ldb), C: [M][N] (ldc) bf16 or f32.
// LDS tiles are XOR-swizzled (slot ^= row&7, 16B slots); staging pre-swizzles the
// GLOBAL source column so global_load_lds' linear dest lands data at the swizzled
// slot (both-sides rule). Grid is 1D with bijective XCD swizzle (nwg % 8 == 0).
template<bool OUT_BF16, bool HAS_BIAS>
__global__ __launch_bounds__(512, 4) void gemm_nt(
    const u16* __restrict__ A, int lda, long long sA,
    const u16* __restrict__ BT, int ldb, long long sB,
    void* __restrict__ Cv, int ldc, long long sC,
    int K, int gx, int gy, const float* __restrict__ bias)
{
  __shared__ u16 As[128][64];
  __shared__ u16 Bs[128][64];
  const int tid = threadIdx.x;
  const int l   = tid & 63;
  const int wid = tid >> 6;       // 0..7
  const int wm  = wid >> 2;       // 0..1 : 64-row half
  const int wn  = wid & 3;        // 0..3 : 32-col quarter

  // bijective XCD swizzle (m-tiles fastest within an XCD chunk -> B-panel reuse)
  const int nwg = gridDim.x;
  const int cpx = nwg >> 3;
  const int bid = blockIdx.x;
  const int wg  = (bid & 7) * cpx + (bid >> 3);
  const int z   = wg / (gx * gy);
  const int rem = wg - z * gx * gy;
  const int by  = rem / gx;
  const int bx  = rem - by * gx;
  const int m0  = bx * 128;
  const int n0  = by * 128;

  A  += (size_t)z * (size_t)sA;
  BT += (size_t)z * (size_t)sB;

  f32x4 acc[4][2] = {};

  const int lr = l >> 3;                 // row within 8-row chunk (0..7)
  const int lc = ((l & 7) ^ lr) * 8;     // pre-swizzled global source slot

  for (int k0 = 0; k0 < K; k0 += 64) {
#pragma unroll
    for (int i = 0; i < 4; ++i) {
      int c = wid * 4 + i;               // 0..31 ; 0..15 = A chunks, 16..31 = B chunks
      if (c < 16) {
        const u16* src = A + (size_t)(m0 + c * 8 + lr) * lda + k0 + lc;
        __builtin_amdgcn_global_load_lds(
            (const __attribute__((address_space(1))) unsigned int*)src,
            (__attribute__((address_space(3))) unsigned int*)&As[c * 8][0],
            16, 0, 0);
      } else {
        int cb = c - 16;
        const u16* src = BT + (size_t)(n0 + cb * 8 + lr) * ldb + k0 + lc;
        __builtin_amdgcn_global_load_lds(
            (const __attribute__((address_space(1))) unsigned int*)src,
            (__attribute__((address_space(3))) unsigned int*)&Bs[cb * 8][0],
            16, 0, 0);
      }
    }
    __syncthreads();
#pragma unroll
    for (int ks = 0; ks < 2; ++ks) {
      short8 af[4], bg[2];
#pragma unroll
      for (int i = 0; i < 4; ++i) {
        int row  = wm * 64 + i * 16 + (l & 15);
        int slot = (ks * 4 + (l >> 4)) ^ (row & 7);
        af[i] = *(const short8*)&As[row][slot * 8];
      }
#pragma unroll
      for (int j = 0; j < 2; ++j) {
        int row  = wn * 32 + j * 16 + (l & 15);
        int slot = (ks * 4 + (l >> 4)) ^ (row & 7);
        bg[j] = *(const short8*)&Bs[row][slot * 8];
      }
#pragma unroll
      for (int i = 0; i < 4; ++i)
#pragma unroll
        for (int j = 0; j < 2; ++j)
          acc[i][j] = __builtin_amdgcn_mfma_f32_16x16x32_bf16(af[i], bg[j], acc[i][j], 0, 0, 0);
    }
    __syncthreads();
  }

  const int rbase = (l >> 4) * 4;
  const int cl    = l & 15;
#pragma unroll
  for (int i = 0; i < 4; ++i) {
#pragma unroll
    for (int j = 0; j < 2; ++j) {
      int col = n0 + wn * 32 + j * 16 + cl;
      float bv_ = HAS_BIAS ? bias[col] : 0.0f;
#pragma unroll
      for (int q = 0; q < 4; ++q) {
        int row = m0 + wm * 64 + i * 16 + rbase + q;
        float v = acc[i][j][q] + bv_;
        if (OUT_BF16)
          ((u16*)Cv)[(size_t)z * (size_t)sC + (size_t)row * ldc + col] = f2bf(v);
        else
          ((float*)Cv)[(size_t)z * (size_t)sC + (size_t)row * ldc + col] = v;
      }
    }
  }
}

// ---------------- K2: transpose V (from qkv cols [256,1024)) -> vT[b][j][t] ----------------
__global__ void transpose_v(const u16* __restrict__ qkv, u16* __restrict__ vT) {
  __shared__ u16 tile[64][72];
  int b  = blockIdx.z;
  int t0 = blockIdx.x * 64;
  int j0 = blockIdx.y * 64;
  int tid = threadIdx.x;
  int tr = tid >> 2;          // 0..63
  int tc = (tid & 3) * 16;    // 0,16,32,48
  const u16* src = qkv + (size_t)(b * SEQ + t0 + tr) * NQKV + 2 * DK + j0 + tc;
  uint4 v0 = *(const uint4*)src;
  uint4 v1 = *(const uint4*)(src + 8);
  *(uint4*)&tile[tr][tc]     = v0;
  *(uint4*)&tile[tr][tc + 8] = v1;
  __syncthreads();
  u16 tmp[16];
#pragma unroll
  for (int u = 0; u < 16; ++u) tmp[u] = tile[tc + u][tr];
  u16* dst = vT + ((size_t)b * DV + j0 + tr) * SEQ + t0 + tc;
  *(uint4*)dst       = *(const uint4*)&tmp[0];
  *(uint4*)(dst + 8) = *(const uint4*)&tmp[8];
}

// ---------------- K4: row softmax in-place on S (bf16), one wave per row ----------------
__global__ __launch_bounds__(256) void softmax_rows(u16* __restrict__ S) {
  int row = blockIdx.x * 4 + (threadIdx.x >> 6);
  int l   = threadIdx.x & 63;
  u16* p = S + (size_t)row * SEQ;
  uint4 d[4];
#pragma unroll
  for (int c = 0; c < 4; ++c) d[c] = *(const uint4*)(p + l * 8 + c * 512);
  float v[32];
  float mx = -1e30f;
#pragma unroll
  for (int c = 0; c < 4; ++c) {
    const u16* u = (const u16*)&d[c];
#pragma unroll
    for (int e = 0; e < 8; ++e) { float f = bf2f(u[e]); v[c * 8 + e] = f; mx = fmaxf(mx, f); }
  }
#pragma unroll
  for (int s = 32; s; s >>= 1) mx = fmaxf(mx, __shfl_xor(mx, s, 64));
  float sum = 0.0f;
#pragma unroll
  for (int e = 0; e < 32; ++e) { float ex = __expf(v[e] - mx); v[e] = ex; sum += ex; }
#pragma unroll
  for (int s = 32; s; s >>= 1) sum += __shfl_xor(sum, s, 64);
  float inv = 1.0f / sum;
#pragma unroll
  for (int c = 0; c < 4; ++c) {
    u16 o[8];
#pragma unroll
    for (int e = 0; e < 8; ++e) o[e] = f2bf(v[c * 8 + e] * inv);
    *(uint4*)(p + l * 8 + c * 512) = *(const uint4*)o;
  }
}

extern "C" void kernel_launch(void* const* d_in, const int* in_sizes, int n_in,
                              void* d_out, int out_size, void* d_ws, size_t ws_size,
                              hipStream_t stream) {
  const float* x  = (const float*)d_in[0];
  const float* Wq = (const float*)d_in[1];
  const float* bq = (const float*)d_in[2];
  const float* Wk = (const float*)d_in[3];
  const float* bk = (const float*)d_in[4];
  const float* Wv = (const float*)d_in[5];
  const float* bv = (const float*)d_in[6];
  float* out = (float*)d_out;

  size_t off = 0;
  auto alloc = [&](size_t bytes) -> void* {
    void* p = (char*)d_ws + off;
    off += (bytes + 255) & ~(size_t)255;
    return p;
  };
  u16*   xb    = (u16*)alloc((size_t)MTOT * DIN * 2);       // 12.6 MB
  u16*   WbT   = (u16*)alloc((size_t)NQKV * DIN * 2);       //  1.6 MB
  float* biasP = (float*)alloc(NQKV * 4);
  u16*   qkv   = (u16*)alloc((size_t)MTOT * NQKV * 2);      // 16.8 MB
  u16*   vT    = (u16*)alloc((size_t)BATCH * DV * SEQ * 2); // 12.6 MB
  u16*   S     = (u16*)alloc((size_t)BATCH * SEQ * SEQ * 2);// 33.6 MB
  if (off > ws_size) return;

  pack_weights<<<dim3(NQKV), dim3(256), 0, stream>>>(Wq, bq, Wk, bk, Wv, bv, WbT, biasP);
  convert_x<<<dim3((MTOT * DIN / 4) / 256), dim3(256), 0, stream>>>(x, xb);

  // qkv = xb @ WbT^T + bias  (M=8192, N=1024, K=768) -> grid 512
  gemm_nt<true, true><<<dim3(64 * 8), dim3(512), 0, stream>>>(
      xb, DIN, 0, WbT, DIN, 0, qkv, NQKV, 0, DIN, 64, 8, biasP);

  transpose_v<<<dim3(SEQ / 64, DV / 64, BATCH), dim3(256), 0, stream>>>(qkv, vT);

  // S = (q*scale) @ k^T per batch  (M=N=2048, K=128) -> grid 1024
  gemm_nt<true, false><<<dim3(16 * 16 * BATCH), dim3(512), 0, stream>>>(
      qkv, NQKV, (long long)SEQ * NQKV,
      qkv + DK, NQKV, (long long)SEQ * NQKV,
      S, SEQ, (long long)SEQ * SEQ, DK, 16, 16, nullptr);

  softmax_rows<<<dim3(MTOT / 4), dim3(256), 0, stream>>>(S);

  // out = P @ vT^T per batch  (M=2048, N=768, K=2048), fp32 out -> grid 384
  gemm_nt<false, false><<<dim3(16 * 6 * BATCH), dim3(512), 0, stream>>>(
      S, SEQ, (long long)SEQ * SEQ,
      vT, SEQ, (long long)DV * SEQ,
      out, DV, (long long)SEQ * DV, SEQ, 16, 6, nullptr);
}

// Round 3
// 102.958 us; speedup vs baseline: 1.1794x; 1.0360x over previous
//
#include <hip/hip_runtime.h>
#include <stdint.h>

typedef unsigned short u16;
typedef __attribute__((ext_vector_type(8))) short short8;
typedef __attribute__((ext_vector_type(4))) float f32x4;

#define BATCH 4
#define SEQ   2048
#define DIN   768
#define DK    128
#define DV    768
#define MTOT  (BATCH*SEQ)   // 8192
#define NQKV  1024          // 128 q + 128 k + 768 v

__device__ __forceinline__ u16 f2bf(float f) {
  union { float f; uint32_t u; } v; v.f = f;
  uint32_t r = v.u + 0x7FFFu + ((v.u >> 16) & 1u);
  return (u16)(r >> 16);
}
__device__ __forceinline__ float bf2f(u16 h) {
  union { uint32_t u; float f; } v; v.u = ((uint32_t)h) << 16;
  return v.f;
}

// ---------------- K0a: pack weights (transposed, bf16) + bias ----------------
// 1/sqrt(DK) folded into Wq/bq.
__global__ void pack_weights(const float* __restrict__ Wq, const float* __restrict__ bq,
                             const float* __restrict__ Wk, const float* __restrict__ bk,
                             const float* __restrict__ Wv, const float* __restrict__ bv,
                             u16* __restrict__ WbT, float* __restrict__ biasP) {
  const float qs = 0.088388347648318447f;  // 1/sqrt(128)
  int n = blockIdx.x;
  if (threadIdx.x == 0) {
    float b = (n < DK) ? bq[n] * qs : (n < 2*DK ? bk[n - DK] : bv[n - 2*DK]);
    biasP[n] = b;
  }
  const float* col; int cn, ldw; float sc;
  if (n < DK)        { col = Wq; cn = n;        ldw = DK; sc = qs;   }
  else if (n < 2*DK) { col = Wk; cn = n - DK;   ldw = DK; sc = 1.0f; }
  else               { col = Wv; cn = n - 2*DK; ldw = DV; sc = 1.0f; }
  for (int i = threadIdx.x; i < DIN; i += blockDim.x) {
    WbT[(size_t)n * DIN + i] = f2bf(col[(size_t)i * ldw + cn] * sc);
  }
}

// ---------------- K0b: convert x fp32 -> bf16 ----------------
__global__ void convert_x(const float* __restrict__ x, u16* __restrict__ xb) {
  int i = (blockIdx.x * blockDim.x + threadIdx.x) * 4;
  float4 v = *(const float4*)(x + i);
  u16 o[4] = { f2bf(v.x), f2bf(v.y), f2bf(v.z), f2bf(v.w) };
  *(uint2*)(xb + i) = *(const uint2*)o;
}

// ---------------- GEMM C = A * BT^T (NT), bf16 in, 128x128 tile, 8 waves ----------------
// Double-buffered LDS (2x32KB): prefetch K-tile t+1 via global_load_lds while
// computing tile t; ONE __syncthreads per K-step (its vmcnt(0) drain lands after
// compute has covered the load latency). XOR-swizzled tiles (both-sides rule:
// pre-swizzled global source column + swizzled ds_read slot). XCD-bijective grid.
template<bool OUT_BF16, bool HAS_BIAS>
__global__ __launch_bounds__(512, 4) void gemm_nt(
    const u16* __restrict__ A, int lda, long long sA,
    const u16* __restrict__ BT, int ldb, long long sB,
    void* __restrict__ Cv, int ldc, long long sC,
    int K, int gx, int gy, const float* __restrict__ bias)
{
  __shared__ u16 As[2][128][64];
  __shared__ u16 Bs[2][128][64];
  const int tid = threadIdx.x;
  const int l   = tid & 63;
  const int wid = tid >> 6;       // 0..7
  const int wm  = wid >> 2;       // 0..1 : 64-row half
  const int wn  = wid & 3;        // 0..3 : 32-col quarter

  const int nwg = gridDim.x;
  const int cpx = nwg >> 3;
  const int bid = blockIdx.x;
  const int wg  = (bid & 7) * cpx + (bid >> 3);
  const int z   = wg / (gx * gy);
  const int rem = wg - z * gx * gy;
  const int by  = rem / gx;
  const int bx  = rem - by * gx;
  const int m0  = bx * 128;
  const int n0  = by * 128;

  A  += (size_t)z * (size_t)sA;
  BT += (size_t)z * (size_t)sB;

  f32x4 acc[4][2] = {};

  const int lr = l >> 3;                 // row within 8-row chunk (0..7)
  const int lc = ((l & 7) ^ lr) * 8;     // pre-swizzled global source slot

  const int ca = wid * 4;                // this wave's first chunk id
  // per-wave: chunks ca..ca+3; 0..15 -> A rows, 16..31 -> B rows
  auto STAGE = [&](int buf, int k0) {
#pragma unroll
    for (int i = 0; i < 4; ++i) {
      int c = ca + i;
      if (c < 16) {
        const u16* src = A + (size_t)(m0 + c * 8 + lr) * lda + k0 + lc;
        __builtin_amdgcn_global_load_lds(
            (const __attribute__((address_space(1))) unsigned int*)src,
            (__attribute__((address_space(3))) unsigned int*)&As[buf][c * 8][0],
            16, 0, 0);
      } else {
        int cb = c - 16;
        const u16* src = BT + (size_t)(n0 + cb * 8 + lr) * ldb + k0 + lc;
        __builtin_amdgcn_global_load_lds(
            (const __attribute__((address_space(1))) unsigned int*)src,
            (__attribute__((address_space(3))) unsigned int*)&Bs[buf][cb * 8][0],
            16, 0, 0);
      }
    }
  };

  STAGE(0, 0);
  __syncthreads();

  int cur = 0;
  for (int k0 = 0; k0 < K; k0 += 64) {
    if (k0 + 64 < K) STAGE(cur ^ 1, k0 + 64);
#pragma unroll
    for (int ks = 0; ks < 2; ++ks) {
      short8 af[4], bg[2];
#pragma unroll
      for (int i = 0; i < 4; ++i) {
        int row  = wm * 64 + i * 16 + (l & 15);
        int slot = (ks * 4 + (l >> 4)) ^ (row & 7);
        af[i] = *(const short8*)&As[cur][row][slot * 8];
      }
#pragma unroll
      for (int j = 0; j < 2; ++j) {
        int row  = wn * 32 + j * 16 + (l & 15);
        int slot = (ks * 4 + (l >> 4)) ^ (row & 7);
        bg[j] = *(const short8*)&Bs[cur][row][slot * 8];
      }
#pragma unroll
      for (int i = 0; i < 4; ++i)
#pragma unroll
        for (int j = 0; j < 2; ++j)
          acc[i][j] = __builtin_amdgcn_mfma_f32_16x16x32_bf16(af[i], bg[j], acc[i][j], 0, 0, 0);
    }
    __syncthreads();   // drains this wave's prefetch vmcnt + guards cur-buffer reuse
    cur ^= 1;
  }

  const int rbase = (l >> 4) * 4;
  const int cl    = l & 15;
#pragma unroll
  for (int i = 0; i < 4; ++i) {
#pragma unroll
    for (int j = 0; j < 2; ++j) {
      int col = n0 + wn * 32 + j * 16 + cl;
      float bv_ = HAS_BIAS ? bias[col] : 0.0f;
#pragma unroll
      for (int q = 0; q < 4; ++q) {
        int row = m0 + wm * 64 + i * 16 + rbase + q;
        float v = acc[i][j][q] + bv_;
        if (OUT_BF16)
          ((u16*)Cv)[(size_t)z * (size_t)sC + (size_t)row * ldc + col] = f2bf(v);
        else
          ((float*)Cv)[(size_t)z * (size_t)sC + (size_t)row * ldc + col] = v;
      }
    }
  }
}

// ---------------- K2: transpose V (from qkv cols [256,1024)) -> vT[b][j][t] ----------------
__global__ void transpose_v(const u16* __restrict__ qkv, u16* __restrict__ vT) {
  __shared__ u16 tile[64][72];
  int b  = blockIdx.z;
  int t0 = blockIdx.x * 64;
  int j0 = blockIdx.y * 64;
  int tid = threadIdx.x;
  int tr = tid >> 2;          // 0..63
  int tc = (tid & 3) * 16;    // 0,16,32,48
  const u16* src = qkv + (size_t)(b * SEQ + t0 + tr) * NQKV + 2 * DK + j0 + tc;
  uint4 v0 = *(const uint4*)src;
  uint4 v1 = *(const uint4*)(src + 8);
  *(uint4*)&tile[tr][tc]     = v0;
  *(uint4*)&tile[tr][tc + 8] = v1;
  __syncthreads();
  u16 tmp[16];
#pragma unroll
  for (int u = 0; u < 16; ++u) tmp[u] = tile[tc + u][tr];
  u16* dst = vT + ((size_t)b * DV + j0 + tr) * SEQ + t0 + tc;
  *(uint4*)dst       = *(const uint4*)&tmp[0];
  *(uint4*)(dst + 8) = *(const uint4*)&tmp[8];
}

// ---------------- K4: row softmax in-place on S (bf16), one wave per row ----------------
__global__ __launch_bounds__(256) void softmax_rows(u16* __restrict__ S) {
  int row = blockIdx.x * 4 + (threadIdx.x >> 6);
  int l   = threadIdx.x & 63;
  u16* p = S + (size_t)row * SEQ;
  uint4 d[4];
#pragma unroll
  for (int c = 0; c < 4; ++c) d[c] = *(const uint4*)(p + l * 8 + c * 512);
  float v[32];
  float mx = -1e30f;
#pragma unroll
  for (int c = 0; c < 4; ++c) {
    const u16* u = (const u16*)&d[c];
#pragma unroll
    for (int e = 0; e < 8; ++e) { float f = bf2f(u[e]); v[c * 8 + e] = f; mx = fmaxf(mx, f); }
  }
#pragma unroll
  for (int s = 32; s; s >>= 1) mx = fmaxf(mx, __shfl_xor(mx, s, 64));
  float sum = 0.0f;
#pragma unroll
  for (int e = 0; e < 32; ++e) { float ex = __expf(v[e] - mx); v[e] = ex; sum += ex; }
#pragma unroll
  for (int s = 32; s; s >>= 1) sum += __shfl_xor(sum, s, 64);
  float inv = 1.0f / sum;
#pragma unroll
  for (int c = 0; c < 4; ++c) {
    u16 o[8];
#pragma unroll
    for (int e = 0; e < 8; ++e) o[e] = f2bf(v[c * 8 + e] * inv);
    *(uint4*)(p + l * 8 + c * 512) = *(const uint4*)o;
  }
}

extern "C" void kernel_launch(void* const* d_in, const int* in_sizes, int n_in,
                              void* d_out, int out_size, void* d_ws, size_t ws_size,
                              hipStream_t stream) {
  const float* x  = (const float*)d_in[0];
  const float* Wq = (const float*)d_in[1];
  const float* bq = (const float*)d_in[2];
  const float* Wk = (const float*)d_in[3];
  const float* bk = (const float*)d_in[4];
  const float* Wv = (const float*)d_in[5];
  const float* bv = (const float*)d_in[6];
  float* out = (float*)d_out;

  size_t off = 0;
  auto alloc = [&](size_t bytes) -> void* {
    void* p = (char*)d_ws + off;
    off += (bytes + 255) & ~(size_t)255;
    return p;
  };
  u16*   xb    = (u16*)alloc((size_t)MTOT * DIN * 2);       // 12.6 MB
  u16*   WbT   = (u16*)alloc((size_t)NQKV * DIN * 2);       //  1.6 MB
  float* biasP = (float*)alloc(NQKV * 4);
  u16*   qkv   = (u16*)alloc((size_t)MTOT * NQKV * 2);      // 16.8 MB
  u16*   vT    = (u16*)alloc((size_t)BATCH * DV * SEQ * 2); // 12.6 MB
  u16*   S     = (u16*)alloc((size_t)BATCH * SEQ * SEQ * 2);// 33.6 MB
  if (off > ws_size) return;

  pack_weights<<<dim3(NQKV), dim3(256), 0, stream>>>(Wq, bq, Wk, bk, Wv, bv, WbT, biasP);
  convert_x<<<dim3((MTOT * DIN / 4) / 256), dim3(256), 0, stream>>>(x, xb);

  // qkv = xb @ WbT^T + bias  (M=8192, N=1024, K=768) -> grid 512
  gemm_nt<true, true><<<dim3(64 * 8), dim3(512), 0, stream>>>(
      xb, DIN, 0, WbT, DIN, 0, qkv, NQKV, 0, DIN, 64, 8, biasP);

  transpose_v<<<dim3(SEQ / 64, DV / 64, BATCH), dim3(256), 0, stream>>>(qkv, vT);

  // S = (q*scale) @ k^T per batch  (M=N=2048, K=128) -> grid 1024
  gemm_nt<true, false><<<dim3(16 * 16 * BATCH), dim3(512), 0, stream>>>(
      qkv, NQKV, (long long)SEQ * NQKV,
      qkv + DK, NQKV, (long long)SEQ * NQKV,
      S, SEQ, (long long)SEQ * SEQ, DK, 16, 16, nullptr);

  softmax_rows<<<dim3(MTOT / 4), dim3(256), 0, stream>>>(S);

  // out = P @ vT^T per batch  (M=2048, N=768, K=2048), fp32 out -> grid 384
  gemm_nt<false, false><<<dim3(16 * 6 * BATCH), dim3(512), 0, stream>>>(
      S, SEQ, (long long)SEQ * SEQ,
      vT, SEQ, (long long)DV * SEQ,
      out, DV, (long long)SEQ * DV, SEQ, 16, 6, nullptr);
}

// Round 4
// 99.142 us; speedup vs baseline: 1.2248x; 1.0385x over previous
//
#include <hip/hip_runtime.h>
#include <stdint.h>

typedef unsigned short u16;
typedef __attribute__((ext_vector_type(8))) short short8;
typedef __attribute__((ext_vector_type(4))) float f32x4;

#define BATCH 4
#define SEQ   2048
#define DIN   768
#define DK    128
#define DV    768
#define MTOT  (BATCH*SEQ)   // 8192
#define NQKV  1024          // 128 q + 128 k + 768 v

__device__ __forceinline__ u16 f2bf(float f) {
  union { float f; uint32_t u; } v; v.f = f;
  uint32_t r = v.u + 0x7FFFu + ((v.u >> 16) & 1u);
  return (u16)(r >> 16);
}
__device__ __forceinline__ float bf2f(u16 h) {
  union { uint32_t u; float f; } v; v.u = ((uint32_t)h) << 16;
  return v.f;
}

// ---------------- K0a: pack weights (transposed, bf16) + bias ----------------
// 1/sqrt(DK) folded into Wq/bq.
__global__ void pack_weights(const float* __restrict__ Wq, const float* __restrict__ bq,
                             const float* __restrict__ Wk, const float* __restrict__ bk,
                             const float* __restrict__ Wv, const float* __restrict__ bv,
                             u16* __restrict__ WbT, float* __restrict__ biasP) {
  const float qs = 0.088388347648318447f;  // 1/sqrt(128)
  int n = blockIdx.x;
  if (threadIdx.x == 0) {
    float b = (n < DK) ? bq[n] * qs : (n < 2*DK ? bk[n - DK] : bv[n - 2*DK]);
    biasP[n] = b;
  }
  const float* col; int cn, ldw; float sc;
  if (n < DK)        { col = Wq; cn = n;        ldw = DK; sc = qs;   }
  else if (n < 2*DK) { col = Wk; cn = n - DK;   ldw = DK; sc = 1.0f; }
  else               { col = Wv; cn = n - 2*DK; ldw = DV; sc = 1.0f; }
  for (int i = threadIdx.x; i < DIN; i += blockDim.x) {
    WbT[(size_t)n * DIN + i] = f2bf(col[(size_t)i * ldw + cn] * sc);
  }
}

// ---------------- K0b: convert x fp32 -> bf16 ----------------
__global__ void convert_x(const float* __restrict__ x, u16* __restrict__ xb) {
  int i = (blockIdx.x * blockDim.x + threadIdx.x) * 4;
  float4 v = *(const float4*)(x + i);
  u16 o[4] = { f2bf(v.x), f2bf(v.y), f2bf(v.z), f2bf(v.w) };
  *(uint2*)(xb + i) = *(const uint2*)o;
}

// ---------------- GEMM C = A * BT^T (NT), bf16 in, 128 x (NJ*64) tile, 8 waves ----------------
// Double-buffered, XOR-swizzled LDS; pre-swizzled global_load_lds staging
// (both-sides rule); bijective XCD grid swizzle.
// MODE 0: C0 = f32 [M][ldc]                       (PV)
// MODE 1: C0 = bf16 [M][ldc]                      (S-GEMM)
// MODE 2: proj epilogue with bias: n0<256 -> C0=qk bf16 [M][256];
//         n0>=256 -> C1=vT bf16 [BATCH][DV][SEQ] written TRANSPOSED.
template<int MODE, int NJ>
__global__ __launch_bounds__(512, 4) void gemm_nt(
    const u16* __restrict__ A, int lda, long long sA,
    const u16* __restrict__ BT, int ldb, long long sB,
    void* __restrict__ C0, void* __restrict__ C1, int ldc, long long sC,
    int K, int gx, int gy, const float* __restrict__ bias)
{
  __shared__ u16 As[2][128][64];
  __shared__ u16 Bs[2][NJ * 64][64];
  const int tid = threadIdx.x;
  const int l   = tid & 63;
  const int wid = tid >> 6;       // 0..7
  const int wm  = wid >> 2;       // 0..1 : 64-row half
  const int wn  = wid & 3;        // 0..3 : (NJ*16)-col quarter

  const int nwg = gridDim.x;
  const int cpx = nwg >> 3;
  const int bid = blockIdx.x;
  const int wg  = (bid & 7) * cpx + (bid >> 3);
  const int z   = wg / (gx * gy);
  const int rem = wg - z * gx * gy;
  const int by  = rem / gx;
  const int bx  = rem - by * gx;
  const int m0  = bx * 128;
  const int n0  = by * (NJ * 64);

  A  += (size_t)z * (size_t)sA;
  BT += (size_t)z * (size_t)sB;

  f32x4 acc[4][NJ] = {};

  const int lr = l >> 3;                 // row within 8-row chunk (0..7)
  const int lc = ((l & 7) ^ lr) * 8;     // pre-swizzled global source slot

  const int CH = 2 + NJ;                 // chunks per wave (A:16 + B:NJ*8 = 8*CH)
  const int ca = wid * CH;
  auto STAGE = [&](int buf, int k0) {
#pragma unroll
    for (int i = 0; i < CH; ++i) {
      int c = ca + i;
      if (c < 16) {
        const u16* src = A + (size_t)(m0 + c * 8 + lr) * lda + k0 + lc;
        __builtin_amdgcn_global_load_lds(
            (const __attribute__((address_space(1))) unsigned int*)src,
            (__attribute__((address_space(3))) unsigned int*)&As[buf][c * 8][0],
            16, 0, 0);
      } else {
        int cb = c - 16;
        const u16* src = BT + (size_t)(n0 + cb * 8 + lr) * ldb + k0 + lc;
        __builtin_amdgcn_global_load_lds(
            (const __attribute__((address_space(1))) unsigned int*)src,
            (__attribute__((address_space(3))) unsigned int*)&Bs[buf][cb * 8][0],
            16, 0, 0);
      }
    }
  };

  STAGE(0, 0);
  __syncthreads();

  int cur = 0;
  for (int k0 = 0; k0 < K; k0 += 64) {
    if (k0 + 64 < K) STAGE(cur ^ 1, k0 + 64);
#pragma unroll
    for (int ks = 0; ks < 2; ++ks) {
      short8 af[4], bg[NJ];
#pragma unroll
      for (int i = 0; i < 4; ++i) {
        int row  = wm * 64 + i * 16 + (l & 15);
        int slot = (ks * 4 + (l >> 4)) ^ (row & 7);
        af[i] = *(const short8*)&As[cur][row][slot * 8];
      }
#pragma unroll
      for (int j = 0; j < NJ; ++j) {
        int row  = wn * (NJ * 16) + j * 16 + (l & 15);
        int slot = (ks * 4 + (l >> 4)) ^ (row & 7);
        bg[j] = *(const short8*)&Bs[cur][row][slot * 8];
      }
#pragma unroll
      for (int i = 0; i < 4; ++i)
#pragma unroll
        for (int j = 0; j < NJ; ++j)
          acc[i][j] = __builtin_amdgcn_mfma_f32_16x16x32_bf16(af[i], bg[j], acc[i][j], 0, 0, 0);
    }
    __syncthreads();
    cur ^= 1;
  }

  const int rbase = (l >> 4) * 4;
  const int cl    = l & 15;
#pragma unroll
  for (int i = 0; i < 4; ++i) {
#pragma unroll
    for (int j = 0; j < NJ; ++j) {
      int col = n0 + wn * (NJ * 16) + j * 16 + cl;
      int row0 = m0 + wm * 64 + i * 16 + rbase;
      if (MODE == 0) {
#pragma unroll
        for (int q = 0; q < 4; ++q)
          ((float*)C0)[(size_t)z * (size_t)sC + (size_t)(row0 + q) * ldc + col] = acc[i][j][q];
      } else if (MODE == 1) {
#pragma unroll
        for (int q = 0; q < 4; ++q)
          ((u16*)C0)[(size_t)z * (size_t)sC + (size_t)(row0 + q) * ldc + col] = f2bf(acc[i][j][q]);
      } else {
        float bv_ = bias[col];
        if (n0 < 256) {
#pragma unroll
          for (int q = 0; q < 4; ++q)
            ((u16*)C0)[(size_t)(row0 + q) * 256 + col] = f2bf(acc[i][j][q] + bv_);
        } else {
          // vT[b][col-256][t], 4 consecutive t -> one 8B store
          int b = row0 >> 11, t = row0 & 2047;
          u16 o[4];
#pragma unroll
          for (int q = 0; q < 4; ++q) o[q] = f2bf(acc[i][j][q] + bv_);
          *(uint2*)&((u16*)C1)[((size_t)b * DV + (col - 256)) * SEQ + t] = *(const uint2*)o;
        }
      }
    }
  }
}

// ---------------- K4: row softmax in-place on S (bf16), one wave per row ----------------
__global__ __launch_bounds__(256) void softmax_rows(u16* __restrict__ S) {
  int row = blockIdx.x * 4 + (threadIdx.x >> 6);
  int l   = threadIdx.x & 63;
  u16* p = S + (size_t)row * SEQ;
  uint4 d[4];
#pragma unroll
  for (int c = 0; c < 4; ++c) d[c] = *(const uint4*)(p + l * 8 + c * 512);
  float v[32];
  float mx = -1e30f;
#pragma unroll
  for (int c = 0; c < 4; ++c) {
    const u16* u = (const u16*)&d[c];
#pragma unroll
    for (int e = 0; e < 8; ++e) { float f = bf2f(u[e]); v[c * 8 + e] = f; mx = fmaxf(mx, f); }
  }
#pragma unroll
  for (int s = 32; s; s >>= 1) mx = fmaxf(mx, __shfl_xor(mx, s, 64));
  float sum = 0.0f;
#pragma unroll
  for (int e = 0; e < 32; ++e) { float ex = __expf(v[e] - mx); v[e] = ex; sum += ex; }
#pragma unroll
  for (int s = 32; s; s >>= 1) sum += __shfl_xor(sum, s, 64);
  float inv = 1.0f / sum;
#pragma unroll
  for (int c = 0; c < 4; ++c) {
    u16 o[8];
#pragma unroll
    for (int e = 0; e < 8; ++e) o[e] = f2bf(v[c * 8 + e] * inv);
    *(uint4*)(p + l * 8 + c * 512) = *(const uint4*)o;
  }
}

extern "C" void kernel_launch(void* const* d_in, const int* in_sizes, int n_in,
                              void* d_out, int out_size, void* d_ws, size_t ws_size,
                              hipStream_t stream) {
  const float* x  = (const float*)d_in[0];
  const float* Wq = (const float*)d_in[1];
  const float* bq = (const float*)d_in[2];
  const float* Wk = (const float*)d_in[3];
  const float* bk = (const float*)d_in[4];
  const float* Wv = (const float*)d_in[5];
  const float* bv = (const float*)d_in[6];
  float* out = (float*)d_out;

  size_t off = 0;
  auto alloc = [&](size_t bytes) -> void* {
    void* p = (char*)d_ws + off;
    off += (bytes + 255) & ~(size_t)255;
    return p;
  };
  u16*   xb    = (u16*)alloc((size_t)MTOT * DIN * 2);       // 12.6 MB
  u16*   WbT   = (u16*)alloc((size_t)NQKV * DIN * 2);       //  1.6 MB
  float* biasP = (float*)alloc(NQKV * 4);
  u16*   qk    = (u16*)alloc((size_t)MTOT * 256 * 2);       //  4.2 MB
  u16*   vT    = (u16*)alloc((size_t)BATCH * DV * SEQ * 2); // 12.6 MB
  u16*   S     = (u16*)alloc((size_t)BATCH * SEQ * SEQ * 2);// 33.6 MB
  if (off > ws_size) return;

  pack_weights<<<dim3(NQKV), dim3(256), 0, stream>>>(Wq, bq, Wk, bk, Wv, bv, WbT, biasP);
  convert_x<<<dim3((MTOT * DIN / 4) / 256), dim3(256), 0, stream>>>(x, xb);

  // proj: [8192,1024] = xb @ WbT^T + bias; writes qk (n<256) and vT (transposed, n>=256)
  gemm_nt<2, 2><<<dim3(64 * 8), dim3(512), 0, stream>>>(
      xb, DIN, 0, WbT, DIN, 0, qk, vT, 0, 0, DIN, 64, 8, biasP);

  // S = (q*scale) @ k^T per batch  (M=N=2048, K=128) -> grid 1024
  gemm_nt<1, 2><<<dim3(16 * 16 * BATCH), dim3(512), 0, stream>>>(
      qk, 256, (long long)SEQ * 256,
      qk + DK, 256, (long long)SEQ * 256,
      S, nullptr, SEQ, (long long)SEQ * SEQ, DK, 16, 16, nullptr);

  softmax_rows<<<dim3(MTOT / 4), dim3(256), 0, stream>>>(S);

  // out = P @ vT^T per batch  (M=2048, N=768 as 4x192, K=2048), fp32 out -> grid 256
  gemm_nt<0, 3><<<dim3(16 * 4 * BATCH), dim3(512), 0, stream>>>(
      S, SEQ, (long long)SEQ * SEQ,
      vT, SEQ, (long long)DV * SEQ,
      out, nullptr, DV, (long long)SEQ * DV, SEQ, 16, 4, nullptr);
}

// Round 5
// 98.722 us; speedup vs baseline: 1.2300x; 1.0043x over previous
//
#include <hip/hip_runtime.h>
#include <stdint.h>

typedef unsigned short u16;
typedef __attribute__((ext_vector_type(8))) short short8;
typedef __attribute__((ext_vector_type(4))) float f32x4;

#define BATCH 4
#define SEQ   2048
#define DIN   768
#define DK    128
#define DV    768
#define MTOT  (BATCH*SEQ)   // 8192
#define NQKV  1024          // 128 q + 128 k + 768 v

__device__ __forceinline__ u16 f2bf(float f) {
  union { float f; uint32_t u; } v; v.f = f;
  uint32_t r = v.u + 0x7FFFu + ((v.u >> 16) & 1u);
  return (u16)(r >> 16);
}
__device__ __forceinline__ float bf2f(u16 h) {
  union { uint32_t u; float f; } v; v.u = ((uint32_t)h) << 16;
  return v.f;
}

// ---------------- K0a: bias pack (1/sqrt(DK) folded into q bias) ----------------
__global__ void pack_bias(const float* __restrict__ bq, const float* __restrict__ bk,
                          const float* __restrict__ bv, float* __restrict__ biasP) {
  const float qs = 0.088388347648318447f;
  int n = blockIdx.x * 256 + threadIdx.x;
  if (n >= NQKV) return;
  biasP[n] = (n < DK) ? bq[n] * qs : (n < 2*DK ? bk[n - DK] : bv[n - 2*DK]);
}

// ---------------- K0b: pack one W (fp32 [DIN][ldw]) -> dst bf16 [ldw][DIN], transposed ----------------
// Coalesced: LDS 64x64 tile transpose. grid (DIN/64, ldw/64).
__global__ __launch_bounds__(256) void pack_weight_t(const float* __restrict__ W,
                                                     u16* __restrict__ dst, int ldw, float sc) {
  __shared__ u16 tile[64][72];
  int i0 = blockIdx.x * 64;   // row block in W (input-dim)
  int n0 = blockIdx.y * 64;   // col block in W (output-dim)
  int tid = threadIdx.x;
  int tr = tid >> 2;          // 0..63
  int tc = (tid & 3) * 16;    // 0,16,32,48
  const float* src = W + (size_t)(i0 + tr) * ldw + n0 + tc;
  u16 o[16];
#pragma unroll
  for (int u = 0; u < 16; u += 4) {
    float4 v = *(const float4*)(src + u);
    o[u] = f2bf(v.x * sc); o[u+1] = f2bf(v.y * sc); o[u+2] = f2bf(v.z * sc); o[u+3] = f2bf(v.w * sc);
  }
  *(uint4*)&tile[tr][tc]     = *(const uint4*)&o[0];
  *(uint4*)&tile[tr][tc + 8] = *(const uint4*)&o[8];
  __syncthreads();
  u16 tmp[16];
#pragma unroll
  for (int u = 0; u < 16; ++u) tmp[u] = tile[tc + u][tr];
  u16* d = dst + (size_t)(n0 + tr) * DIN + i0 + tc;
  *(uint4*)d       = *(const uint4*)&tmp[0];
  *(uint4*)(d + 8) = *(const uint4*)&tmp[8];
}

// ---------------- K0c: convert x fp32 -> bf16 ----------------
__global__ void convert_x(const float* __restrict__ x, u16* __restrict__ xb) {
  int i = (blockIdx.x * blockDim.x + threadIdx.x) * 4;
  float4 v = *(const float4*)(x + i);
  u16 o[4] = { f2bf(v.x), f2bf(v.y), f2bf(v.z), f2bf(v.w) };
  *(uint2*)(xb + i) = *(const uint2*)o;
}

// ---------------- GEMM C = A * BT^T (NT), bf16 in, 128 x (NJ*64) tile, 8 waves ----------------
// Double-buffered, XOR-swizzled LDS; pre-swizzled global_load_lds staging
// (both-sides rule); bijective XCD grid swizzle.
// MODE 0: C0 = f32 [M][ldc], scaled by rsum[z*SEQ+row] (PV with softmax divide)
// MODE 1: C0 = bf16 [M][ldc] storing exp(acc)        (S-GEMM -> P)
// MODE 2: proj epilogue with bias: n0<256 -> C0=qk bf16 [M][256];
//         n0>=256 -> C1=vT bf16 [BATCH][DV][SEQ] written TRANSPOSED.
template<int MODE, int NJ>
__global__ __launch_bounds__(512, 4) void gemm_nt(
    const u16* __restrict__ A, int lda, long long sA,
    const u16* __restrict__ BT, int ldb, long long sB,
    void* __restrict__ C0, void* __restrict__ C1, int ldc, long long sC,
    int K, int gx, int gy, const float* __restrict__ bias,
    const float* __restrict__ rsum)
{
  __shared__ u16 As[2][128][64];
  __shared__ u16 Bs[2][NJ * 64][64];
  const int tid = threadIdx.x;
  const int l   = tid & 63;
  const int wid = tid >> 6;       // 0..7
  const int wm  = wid >> 2;       // 0..1 : 64-row half
  const int wn  = wid & 3;        // 0..3 : (NJ*16)-col quarter

  const int nwg = gridDim.x;
  const int cpx = nwg >> 3;
  const int bid = blockIdx.x;
  const int wg  = (bid & 7) * cpx + (bid >> 3);
  const int z   = wg / (gx * gy);
  const int rem = wg - z * gx * gy;
  const int by  = rem / gx;
  const int bx  = rem - by * gx;
  const int m0  = bx * 128;
  const int n0  = by * (NJ * 64);

  A  += (size_t)z * (size_t)sA;
  BT += (size_t)z * (size_t)sB;

  f32x4 acc[4][NJ] = {};

  const int lr = l >> 3;                 // row within 8-row chunk (0..7)
  const int lc = ((l & 7) ^ lr) * 8;     // pre-swizzled global source slot

  const int CH = 2 + NJ;                 // chunks per wave (A:16 + B:NJ*8 = 8*CH)
  const int ca = wid * CH;
  auto STAGE = [&](int buf, int k0) {
#pragma unroll
    for (int i = 0; i < CH; ++i) {
      int c = ca + i;
      if (c < 16) {
        const u16* src = A + (size_t)(m0 + c * 8 + lr) * lda + k0 + lc;
        __builtin_amdgcn_global_load_lds(
            (const __attribute__((address_space(1))) unsigned int*)src,
            (__attribute__((address_space(3))) unsigned int*)&As[buf][c * 8][0],
            16, 0, 0);
      } else {
        int cb = c - 16;
        const u16* src = BT + (size_t)(n0 + cb * 8 + lr) * ldb + k0 + lc;
        __builtin_amdgcn_global_load_lds(
            (const __attribute__((address_space(1))) unsigned int*)src,
            (__attribute__((address_space(3))) unsigned int*)&Bs[buf][cb * 8][0],
            16, 0, 0);
      }
    }
  };

  STAGE(0, 0);
  __syncthreads();

  int cur = 0;
  for (int k0 = 0; k0 < K; k0 += 64) {
    if (k0 + 64 < K) STAGE(cur ^ 1, k0 + 64);
#pragma unroll
    for (int ks = 0; ks < 2; ++ks) {
      short8 af[4], bg[NJ];
#pragma unroll
      for (int i = 0; i < 4; ++i) {
        int row  = wm * 64 + i * 16 + (l & 15);
        int slot = (ks * 4 + (l >> 4)) ^ (row & 7);
        af[i] = *(const short8*)&As[cur][row][slot * 8];
      }
#pragma unroll
      for (int j = 0; j < NJ; ++j) {
        int row  = wn * (NJ * 16) + j * 16 + (l & 15);
        int slot = (ks * 4 + (l >> 4)) ^ (row & 7);
        bg[j] = *(const short8*)&Bs[cur][row][slot * 8];
      }
#pragma unroll
      for (int i = 0; i < 4; ++i)
#pragma unroll
        for (int j = 0; j < NJ; ++j)
          acc[i][j] = __builtin_amdgcn_mfma_f32_16x16x32_bf16(af[i], bg[j], acc[i][j], 0, 0, 0);
    }
    __syncthreads();
    cur ^= 1;
  }

  const int rbase = (l >> 4) * 4;
  const int cl    = l & 15;
#pragma unroll
  for (int i = 0; i < 4; ++i) {
#pragma unroll
    for (int j = 0; j < NJ; ++j) {
      int col = n0 + wn * (NJ * 16) + j * 16 + cl;
      int row0 = m0 + wm * 64 + i * 16 + rbase;
      if (MODE == 0) {
#pragma unroll
        for (int q = 0; q < 4; ++q) {
          float rs = rsum[(size_t)z * SEQ + row0 + q];
          ((float*)C0)[(size_t)z * (size_t)sC + (size_t)(row0 + q) * ldc + col] = acc[i][j][q] * rs;
        }
      } else if (MODE == 1) {
#pragma unroll
        for (int q = 0; q < 4; ++q)
          ((u16*)C0)[(size_t)z * (size_t)sC + (size_t)(row0 + q) * ldc + col] = f2bf(__expf(acc[i][j][q]));
      } else {
        float bv_ = bias[col];
        if (n0 < 256) {
#pragma unroll
          for (int q = 0; q < 4; ++q)
            ((u16*)C0)[(size_t)(row0 + q) * 256 + col] = f2bf(acc[i][j][q] + bv_);
        } else {
          // vT[b][col-256][t], 4 consecutive t -> one 8B store
          int b = row0 >> 11, t = row0 & 2047;
          u16 o[4];
#pragma unroll
          for (int q = 0; q < 4; ++q) o[q] = f2bf(acc[i][j][q] + bv_);
          *(uint2*)&((u16*)C1)[((size_t)b * DV + (col - 256)) * SEQ + t] = *(const uint2*)o;
        }
      }
    }
  }
}

// ---------------- K4: row-sum of P (bf16), store 1/sum; one wave per row ----------------
__global__ __launch_bounds__(256) void rowsum_inv(const u16* __restrict__ P, float* __restrict__ rinv) {
  int row = blockIdx.x * 4 + (threadIdx.x >> 6);
  int l   = threadIdx.x & 63;
  const u16* p = P + (size_t)row * SEQ;
  float s = 0.0f;
#pragma unroll
  for (int c = 0; c < 4; ++c) {
    uint4 d = *(const uint4*)(p + l * 8 + c * 512);
    const u16* u = (const u16*)&d;
#pragma unroll
    for (int e = 0; e < 8; ++e) s += bf2f(u[e]);
  }
#pragma unroll
  for (int sft = 32; sft; sft >>= 1) s += __shfl_xor(s, sft, 64);
  if (l == 0) rinv[row] = 1.0f / s;
}

extern "C" void kernel_launch(void* const* d_in, const int* in_sizes, int n_in,
                              void* d_out, int out_size, void* d_ws, size_t ws_size,
                              hipStream_t stream) {
  const float* x  = (const float*)d_in[0];
  const float* Wq = (const float*)d_in[1];
  const float* bq = (const float*)d_in[2];
  const float* Wk = (const float*)d_in[3];
  const float* bk = (const float*)d_in[4];
  const float* Wv = (const float*)d_in[5];
  const float* bv = (const float*)d_in[6];
  float* out = (float*)d_out;

  size_t off = 0;
  auto alloc = [&](size_t bytes) -> void* {
    void* p = (char*)d_ws + off;
    off += (bytes + 255) & ~(size_t)255;
    return p;
  };
  u16*   xb    = (u16*)alloc((size_t)MTOT * DIN * 2);       // 12.6 MB
  u16*   WbT   = (u16*)alloc((size_t)NQKV * DIN * 2);       //  1.6 MB
  float* biasP = (float*)alloc(NQKV * 4);
  u16*   qk    = (u16*)alloc((size_t)MTOT * 256 * 2);       //  4.2 MB
  u16*   vT    = (u16*)alloc((size_t)BATCH * DV * SEQ * 2); // 12.6 MB
  u16*   P     = (u16*)alloc((size_t)BATCH * SEQ * SEQ * 2);// 33.6 MB
  float* rinv  = (float*)alloc((size_t)MTOT * 4);           // 32 KB
  if (off > ws_size) return;

  const float qs = 0.088388347648318447f;  // 1/sqrt(128)

  pack_bias<<<dim3(4), dim3(256), 0, stream>>>(bq, bk, bv, biasP);
  pack_weight_t<<<dim3(DIN/64, DK/64), dim3(256), 0, stream>>>(Wq, WbT, DK, qs);
  pack_weight_t<<<dim3(DIN/64, DK/64), dim3(256), 0, stream>>>(Wk, WbT + (size_t)DK*DIN, DK, 1.0f);
  pack_weight_t<<<dim3(DIN/64, DV/64), dim3(256), 0, stream>>>(Wv, WbT + (size_t)2*DK*DIN, DV, 1.0f);
  convert_x<<<dim3((MTOT * DIN / 4) / 256), dim3(256), 0, stream>>>(x, xb);

  // proj: [8192,1024] = xb @ WbT^T + bias; writes qk (n<256) and vT (transposed, n>=256)
  gemm_nt<2, 2><<<dim3(64 * 8), dim3(512), 0, stream>>>(
      xb, DIN, 0, WbT, DIN, 0, qk, vT, 0, 0, DIN, 64, 8, biasP, nullptr);

  // P = exp(q_scaled @ k^T) per batch  (M=N=2048, K=128) -> grid 1024
  gemm_nt<1, 2><<<dim3(16 * 16 * BATCH), dim3(512), 0, stream>>>(
      qk, 256, (long long)SEQ * 256,
      qk + DK, 256, (long long)SEQ * 256,
      P, nullptr, SEQ, (long long)SEQ * SEQ, DK, 16, 16, nullptr, nullptr);

  rowsum_inv<<<dim3(MTOT / 4), dim3(256), 0, stream>>>(P, rinv);

  // out = (P @ vT^T) * rinv per batch  (M=2048, N=768 as 4x192, K=2048), fp32 out -> grid 256
  gemm_nt<0, 3><<<dim3(16 * 4 * BATCH), dim3(512), 0, stream>>>(
      P, SEQ, (long long)SEQ * SEQ,
      vT, SEQ, (long long)DV * SEQ,
      out, nullptr, DV, (long long)SEQ * DV, SEQ, 16, 4, nullptr, rinv);
}

// Round 6
// 86.549 us; speedup vs baseline: 1.4030x; 1.1406x over previous
//
#include <hip/hip_runtime.h>
#include <stdint.h>

typedef unsigned short u16;
typedef __attribute__((ext_vector_type(8))) short short8;
typedef __attribute__((ext_vector_type(4))) float f32x4;

#define BATCH 4
#define SEQ   2048
#define DIN   768
#define DK    128
#define DV    768
#define MTOT  (BATCH*SEQ)   // 8192
#define NQKV  1024          // 128 q + 128 k + 768 v

__device__ __forceinline__ u16 f2bf(float f) {
  union { float f; uint32_t u; } v; v.f = f;
  uint32_t r = v.u + 0x7FFFu + ((v.u >> 16) & 1u);
  return (u16)(r >> 16);
}
__device__ __forceinline__ float bf2f(u16 h) {
  union { uint32_t u; float f; } v; v.u = ((uint32_t)h) << 16;
  return v.f;
}

// ---------------- K0a: pack ALL weights (transposed, bf16) + bias, one dispatch ----------------
// grid (DIN/64=12, 16): y 0-1 -> Wq, 2-3 -> Wk, 4-15 -> Wv. Block (0,0) also packs bias.
__global__ __launch_bounds__(256) void pack_all(
    const float* __restrict__ Wq, const float* __restrict__ bq,
    const float* __restrict__ Wk, const float* __restrict__ bk,
    const float* __restrict__ Wv, const float* __restrict__ bv,
    u16* __restrict__ WbT, float* __restrict__ biasP) {
  const float qs = 0.088388347648318447f;  // 1/sqrt(128)
  __shared__ u16 tile[64][72];
  int y = blockIdx.y;
  const float* W; u16* dst; int ldw, nb; float sc;
  if (y < 2)      { W = Wq; dst = WbT;                       ldw = DK; sc = qs;   nb = y;     }
  else if (y < 4) { W = Wk; dst = WbT + (size_t)DK * DIN;    ldw = DK; sc = 1.0f; nb = y - 2; }
  else            { W = Wv; dst = WbT + (size_t)2*DK * DIN;  ldw = DV; sc = 1.0f; nb = y - 4; }
  int i0 = blockIdx.x * 64;
  int n0 = nb * 64;
  int tid = threadIdx.x;
  if (blockIdx.x == 0 && y == 0) {
    for (int n = tid; n < NQKV; n += 256)
      biasP[n] = (n < DK) ? bq[n] * qs : (n < 2*DK ? bk[n - DK] : bv[n - 2*DK]);
  }
  int tr = tid >> 2;          // 0..63
  int tc = (tid & 3) * 16;    // 0,16,32,48
  const float* src = W + (size_t)(i0 + tr) * ldw + n0 + tc;
  u16 o[16];
#pragma unroll
  for (int u = 0; u < 16; u += 4) {
    float4 v = *(const float4*)(src + u);
    o[u] = f2bf(v.x * sc); o[u+1] = f2bf(v.y * sc); o[u+2] = f2bf(v.z * sc); o[u+3] = f2bf(v.w * sc);
  }
  *(uint4*)&tile[tr][tc]     = *(const uint4*)&o[0];
  *(uint4*)&tile[tr][tc + 8] = *(const uint4*)&o[8];
  __syncthreads();
  u16 tmp[16];
#pragma unroll
  for (int u = 0; u < 16; ++u) tmp[u] = tile[tc + u][tr];
  u16* d = dst + (size_t)(n0 + tr) * DIN + i0 + tc;
  *(uint4*)d       = *(const uint4*)&tmp[0];
  *(uint4*)(d + 8) = *(const uint4*)&tmp[8];
}

// ---------------- K0b: convert x fp32 -> bf16 ----------------
__global__ void convert_x(const float* __restrict__ x, u16* __restrict__ xb) {
  int i = (blockIdx.x * blockDim.x + threadIdx.x) * 4;
  float4 v = *(const float4*)(x + i);
  u16 o[4] = { f2bf(v.x), f2bf(v.y), f2bf(v.z), f2bf(v.w) };
  *(uint2*)(xb + i) = *(const uint2*)o;
}

// ---------------- GEMM C = A * BT^T (NT), bf16 in, 128 x (NJ*64) tile, 8 waves ----------------
// Double-buffered, XOR-swizzled LDS; pre-swizzled global_load_lds staging
// (both-sides rule); bijective XCD grid swizzle.
// MODE 0: PV: C0 = f32 [M][ldc]; row-sums of A-tile accumulated in-kernel via
//         ones-MFMA (B = constant 1.0 fragment); out = acc / rowsum.
// MODE 2: proj epilogue with bias: n0<256 -> C0=qk bf16 [M][256];
//         n0>=256 -> C1=vT bf16 [BATCH][DV][SEQ] written TRANSPOSED.
template<int MODE, int NJ>
__global__ __launch_bounds__(512, 4) void gemm_nt(
    const u16* __restrict__ A, int lda, long long sA,
    const u16* __restrict__ BT, int ldb, long long sB,
    void* __restrict__ C0, void* __restrict__ C1, int ldc, long long sC,
    int K, int gx, int gy, const float* __restrict__ bias)
{
  __shared__ u16 As[2][128][64];
  __shared__ u16 Bs[2][NJ * 64][64];
  const int tid = threadIdx.x;
  const int l   = tid & 63;
  const int wid = tid >> 6;       // 0..7
  const int wm  = wid >> 2;       // 0..1 : 64-row half
  const int wn  = wid & 3;        // 0..3 : (NJ*16)-col quarter

  const int nwg = gridDim.x;
  const int cpx = nwg >> 3;
  const int bid = blockIdx.x;
  const int wg  = (bid & 7) * cpx + (bid >> 3);
  const int z   = wg / (gx * gy);
  const int rem = wg - z * gx * gy;
  const int by  = rem / gx;
  const int bx  = rem - by * gx;
  const int m0  = bx * 128;
  const int n0  = by * (NJ * 64);

  A  += (size_t)z * (size_t)sA;
  BT += (size_t)z * (size_t)sB;

  f32x4 acc[4][NJ] = {};
  f32x4 accO[4] = {};                     // MODE 0: row sums
  const short8 kOnes = {16256,16256,16256,16256,16256,16256,16256,16256}; // bf16 1.0 x8

  const int lr = l >> 3;                 // row within 8-row chunk (0..7)
  const int lc = ((l & 7) ^ lr) * 8;     // pre-swizzled global source slot

  const int CH = 2 + NJ;                 // chunks per wave (A:16 + B:NJ*8 = 8*CH)
  const int ca = wid * CH;
  auto STAGE = [&](int buf, int k0) {
#pragma unroll
    for (int i = 0; i < CH; ++i) {
      int c = ca + i;
      if (c < 16) {
        const u16* src = A + (size_t)(m0 + c * 8 + lr) * lda + k0 + lc;
        __builtin_amdgcn_global_load_lds(
            (const __attribute__((address_space(1))) unsigned int*)src,
            (__attribute__((address_space(3))) unsigned int*)&As[buf][c * 8][0],
            16, 0, 0);
      } else {
        int cb = c - 16;
        const u16* src = BT + (size_t)(n0 + cb * 8 + lr) * ldb + k0 + lc;
        __builtin_amdgcn_global_load_lds(
            (const __attribute__((address_space(1))) unsigned int*)src,
            (__attribute__((address_space(3))) unsigned int*)&Bs[buf][cb * 8][0],
            16, 0, 0);
      }
    }
  };

  STAGE(0, 0);
  __syncthreads();

  int cur = 0;
  for (int k0 = 0; k0 < K; k0 += 64) {
    if (k0 + 64 < K) STAGE(cur ^ 1, k0 + 64);
#pragma unroll
    for (int ks = 0; ks < 2; ++ks) {
      short8 af[4], bg[NJ];
#pragma unroll
      for (int i = 0; i < 4; ++i) {
        int row  = wm * 64 + i * 16 + (l & 15);
        int slot = (ks * 4 + (l >> 4)) ^ (row & 7);
        af[i] = *(const short8*)&As[cur][row][slot * 8];
      }
#pragma unroll
      for (int j = 0; j < NJ; ++j) {
        int row  = wn * (NJ * 16) + j * 16 + (l & 15);
        int slot = (ks * 4 + (l >> 4)) ^ (row & 7);
        bg[j] = *(const short8*)&Bs[cur][row][slot * 8];
      }
#pragma unroll
      for (int i = 0; i < 4; ++i)
#pragma unroll
        for (int j = 0; j < NJ; ++j)
          acc[i][j] = __builtin_amdgcn_mfma_f32_16x16x32_bf16(af[i], bg[j], acc[i][j], 0, 0, 0);
      if (MODE == 0) {
#pragma unroll
        for (int i = 0; i < 4; ++i)
          accO[i] = __builtin_amdgcn_mfma_f32_16x16x32_bf16(af[i], kOnes, accO[i], 0, 0, 0);
      }
    }
    __syncthreads();
    cur ^= 1;
  }

  const int rbase = (l >> 4) * 4;
  const int cl    = l & 15;
#pragma unroll
  for (int i = 0; i < 4; ++i) {
    f32x4 rs;
    if (MODE == 0) {
#pragma unroll
      for (int q = 0; q < 4; ++q) rs[q] = 1.0f / accO[i][q];
    }
#pragma unroll
    for (int j = 0; j < NJ; ++j) {
      int col = n0 + wn * (NJ * 16) + j * 16 + cl;
      int row0 = m0 + wm * 64 + i * 16 + rbase;
      if (MODE == 0) {
#pragma unroll
        for (int q = 0; q < 4; ++q)
          ((float*)C0)[(size_t)z * (size_t)sC + (size_t)(row0 + q) * ldc + col] = acc[i][j][q] * rs[q];
      } else {
        float bv_ = bias[col];
        if (n0 < 256) {
#pragma unroll
          for (int q = 0; q < 4; ++q)
            ((u16*)C0)[(size_t)(row0 + q) * 256 + col] = f2bf(acc[i][j][q] + bv_);
        } else {
          // vT[b][col-256][t], 4 consecutive t -> one 8B store
          int b = row0 >> 11, t = row0 & 2047;
          u16 o[4];
#pragma unroll
          for (int q = 0; q < 4; ++q) o[q] = f2bf(acc[i][j][q] + bv_);
          *(uint2*)&((u16*)C1)[((size_t)b * DV + (col - 256)) * SEQ + t] = *(const uint2*)o;
        }
      }
    }
  }
}

// ---------------- K3: S-GEMM, K=128 single-stage: P = exp(q_s @ k^T), bf16 out ----------------
// Whole K staged at once: As[128][128] + Bs[128][128] = 64KB LDS, one barrier.
__global__ __launch_bounds__(512, 4) void sgemm_exp(
    const u16* __restrict__ qk, u16* __restrict__ P)
{
  __shared__ u16 As[128][128];
  __shared__ u16 Bs[128][128];
  const int tid = threadIdx.x;
  const int l   = tid & 63;
  const int wid = tid >> 6;
  const int wm  = wid >> 2;       // 0..1
  const int wn  = wid & 3;        // 0..3

  const int nwg = gridDim.x;      // 1024
  const int cpx = nwg >> 3;
  const int bid = blockIdx.x;
  const int wg  = (bid & 7) * cpx + (bid >> 3);
  const int z   = wg >> 8;        // /256
  const int rem = wg & 255;
  const int by  = rem >> 4;
  const int bx  = rem & 15;
  const int m0  = bx * 128;
  const int n0  = by * 128;

  const u16* A  = qk + (size_t)z * SEQ * 256;        // q rows, lda=256
  const u16* BT = qk + DK + (size_t)z * SEQ * 256;   // k rows, ldb=256

  // stage: 64 chunks of 4 rows x 16 slots; wave w owns chunks w*8..w*8+7
  const int rin  = l >> 4;        // row within chunk
  const int s16  = l & 15;        // 16B slot
#pragma unroll
  for (int i = 0; i < 8; ++i) {
    int c = wid * 8 + i;
    if (c < 32) {
      int r = c * 4 + rin;
      int gs = s16 ^ (r & 7);
      const u16* src = A + (size_t)(m0 + r) * 256 + gs * 8;
      __builtin_amdgcn_global_load_lds(
          (const __attribute__((address_space(1))) unsigned int*)src,
          (__attribute__((address_space(3))) unsigned int*)&As[c * 4][0],
          16, 0, 0);
    } else {
      int cb = c - 32;
      int r = cb * 4 + rin;
      int gs = s16 ^ (r & 7);
      const u16* src = BT + (size_t)(n0 + r) * 256 + gs * 8;
      __builtin_amdgcn_global_load_lds(
          (const __attribute__((address_space(1))) unsigned int*)src,
          (__attribute__((address_space(3))) unsigned int*)&Bs[cb * 4][0],
          16, 0, 0);
    }
  }
  __syncthreads();

  f32x4 acc[4][2] = {};
#pragma unroll
  for (int ks = 0; ks < 4; ++ks) {
    short8 af[4], bg[2];
#pragma unroll
    for (int i = 0; i < 4; ++i) {
      int row  = wm * 64 + i * 16 + (l & 15);
      int slot = (ks * 4 + (l >> 4)) ^ (row & 7);
      af[i] = *(const short8*)&As[row][slot * 8];
    }
#pragma unroll
    for (int j = 0; j < 2; ++j) {
      int row  = wn * 32 + j * 16 + (l & 15);
      int slot = (ks * 4 + (l >> 4)) ^ (row & 7);
      bg[j] = *(const short8*)&Bs[row][slot * 8];
    }
#pragma unroll
    for (int i = 0; i < 4; ++i)
#pragma unroll
      for (int j = 0; j < 2; ++j)
        acc[i][j] = __builtin_amdgcn_mfma_f32_16x16x32_bf16(af[i], bg[j], acc[i][j], 0, 0, 0);
  }

  const int rbase = (l >> 4) * 4;
  const int cl    = l & 15;
  u16* Pz = P + (size_t)z * SEQ * SEQ;
#pragma unroll
  for (int i = 0; i < 4; ++i)
#pragma unroll
    for (int j = 0; j < 2; ++j) {
      int col  = n0 + wn * 32 + j * 16 + cl;
      int row0 = m0 + wm * 64 + i * 16 + rbase;
#pragma unroll
      for (int q = 0; q < 4; ++q)
        Pz[(size_t)(row0 + q) * SEQ + col] = f2bf(__expf(acc[i][j][q]));
    }
}

extern "C" void kernel_launch(void* const* d_in, const int* in_sizes, int n_in,
                              void* d_out, int out_size, void* d_ws, size_t ws_size,
                              hipStream_t stream) {
  const float* x  = (const float*)d_in[0];
  const float* Wq = (const float*)d_in[1];
  const float* bq = (const float*)d_in[2];
  const float* Wk = (const float*)d_in[3];
  const float* bk = (const float*)d_in[4];
  const float* Wv = (const float*)d_in[5];
  const float* bv = (const float*)d_in[6];
  float* out = (float*)d_out;

  size_t off = 0;
  auto alloc = [&](size_t bytes) -> void* {
    void* p = (char*)d_ws + off;
    off += (bytes + 255) & ~(size_t)255;
    return p;
  };
  u16*   xb    = (u16*)alloc((size_t)MTOT * DIN * 2);       // 12.6 MB
  u16*   WbT   = (u16*)alloc((size_t)NQKV * DIN * 2);       //  1.6 MB
  float* biasP = (float*)alloc(NQKV * 4);
  u16*   qk    = (u16*)alloc((size_t)MTOT * 256 * 2);       //  4.2 MB
  u16*   vT    = (u16*)alloc((size_t)BATCH * DV * SEQ * 2); // 12.6 MB
  u16*   P     = (u16*)alloc((size_t)BATCH * SEQ * SEQ * 2);// 33.6 MB
  if (off > ws_size) return;

  pack_all<<<dim3(DIN/64, 16), dim3(256), 0, stream>>>(Wq, bq, Wk, bk, Wv, bv, WbT, biasP);
  convert_x<<<dim3((MTOT * DIN / 4) / 256), dim3(256), 0, stream>>>(x, xb);

  // proj: [8192,1024] = xb @ WbT^T + bias; writes qk (n<256) and vT (transposed, n>=256)
  gemm_nt<2, 2><<<dim3(64 * 8), dim3(512), 0, stream>>>(
      xb, DIN, 0, WbT, DIN, 0, qk, vT, 0, 0, DIN, 64, 8, biasP);

  // P = exp(q_scaled @ k^T) per batch (M=N=2048, K=128), single-stage
  sgemm_exp<<<dim3(16 * 16 * BATCH), dim3(512), 0, stream>>>(qk, P);

  // out = (P @ vT^T) / rowsum(P) per batch (M=2048, N=768 as 4x192, K=2048), fp32 out
  gemm_nt<0, 3><<<dim3(16 * 4 * BATCH), dim3(512), 0, stream>>>(
      P, SEQ, (long long)SEQ * SEQ,
      vT, SEQ, (long long)DV * SEQ,
      out, nullptr, DV, (long long)SEQ * DV, SEQ, 16, 4, nullptr);
}

// Round 7
// 85.519 us; speedup vs baseline: 1.4199x; 1.0120x over previous
//
#include <hip/hip_runtime.h>
#include <stdint.h>

typedef unsigned short u16;
typedef __attribute__((ext_vector_type(8))) short short8;
typedef __attribute__((ext_vector_type(4))) float f32x4;

#define BATCH 4
#define SEQ   2048
#define DIN   768
#define DK    128
#define DV    768
#define MTOT  (BATCH*SEQ)   // 8192
#define NQKV  1024          // 128 q + 128 k + 768 v

__device__ __forceinline__ u16 f2bf(float f) {
  union { float f; uint32_t u; } v; v.f = f;
  uint32_t r = v.u + 0x7FFFu + ((v.u >> 16) & 1u);
  return (u16)(r >> 16);
}
__device__ __forceinline__ float bf2f(u16 h) {
  union { uint32_t u; float f; } v; v.u = ((uint32_t)h) << 16;
  return v.f;
}

template<int N> __device__ __forceinline__ void wait_vmcnt() {
  if constexpr (N == 0) asm volatile("s_waitcnt vmcnt(0)" ::: "memory");
  else if constexpr (N == 5) asm volatile("s_waitcnt vmcnt(5)" ::: "memory");
  else if constexpr (N == 10) asm volatile("s_waitcnt vmcnt(10)" ::: "memory");
}

// ---------------- K0a: pack ALL weights (transposed, bf16) + bias, one dispatch ----------------
__global__ __launch_bounds__(256) void pack_all(
    const float* __restrict__ Wq, const float* __restrict__ bq,
    const float* __restrict__ Wk, const float* __restrict__ bk,
    const float* __restrict__ Wv, const float* __restrict__ bv,
    u16* __restrict__ WbT, float* __restrict__ biasP) {
  const float qs = 0.088388347648318447f;  // 1/sqrt(128)
  __shared__ u16 tile[64][72];
  int y = blockIdx.y;
  const float* W; u16* dst; int ldw, nb; float sc;
  if (y < 2)      { W = Wq; dst = WbT;                       ldw = DK; sc = qs;   nb = y;     }
  else if (y < 4) { W = Wk; dst = WbT + (size_t)DK * DIN;    ldw = DK; sc = 1.0f; nb = y - 2; }
  else            { W = Wv; dst = WbT + (size_t)2*DK * DIN;  ldw = DV; sc = 1.0f; nb = y - 4; }
  int i0 = blockIdx.x * 64;
  int n0 = nb * 64;
  int tid = threadIdx.x;
  if (blockIdx.x == 0 && y == 0) {
    for (int n = tid; n < NQKV; n += 256)
      biasP[n] = (n < DK) ? bq[n] * qs : (n < 2*DK ? bk[n - DK] : bv[n - 2*DK]);
  }
  int tr = tid >> 2;
  int tc = (tid & 3) * 16;
  const float* src = W + (size_t)(i0 + tr) * ldw + n0 + tc;
  u16 o[16];
#pragma unroll
  for (int u = 0; u < 16; u += 4) {
    float4 v = *(const float4*)(src + u);
    o[u] = f2bf(v.x * sc); o[u+1] = f2bf(v.y * sc); o[u+2] = f2bf(v.z * sc); o[u+3] = f2bf(v.w * sc);
  }
  *(uint4*)&tile[tr][tc]     = *(const uint4*)&o[0];
  *(uint4*)&tile[tr][tc + 8] = *(const uint4*)&o[8];
  __syncthreads();
  u16 tmp[16];
#pragma unroll
  for (int u = 0; u < 16; ++u) tmp[u] = tile[tc + u][tr];
  u16* d = dst + (size_t)(n0 + tr) * DIN + i0 + tc;
  *(uint4*)d       = *(const uint4*)&tmp[0];
  *(uint4*)(d + 8) = *(const uint4*)&tmp[8];
}

// ---------------- K0b: convert x fp32 -> bf16 ----------------
__global__ void convert_x(const float* __restrict__ x, u16* __restrict__ xb) {
  int i = (blockIdx.x * blockDim.x + threadIdx.x) * 4;
  float4 v = *(const float4*)(x + i);
  u16 o[4] = { f2bf(v.x), f2bf(v.y), f2bf(v.z), f2bf(v.w) };
  *(uint2*)(xb + i) = *(const uint2*)o;
}

// ---------------- proj GEMM (2-phase dbuf, unchanged): qkv projection ----------------
// n0<256 -> C0=qk bf16 [M][256]; n0>=256 -> C1=vT bf16 [BATCH][DV][SEQ] TRANSPOSED.
__global__ __launch_bounds__(512, 4) void gemm_proj(
    const u16* __restrict__ A, const u16* __restrict__ BT,
    u16* __restrict__ C0, u16* __restrict__ C1,
    const float* __restrict__ bias)
{
  const int NJ = 2, CH = 4, gx = 64;
  __shared__ u16 As[2][128][64];
  __shared__ u16 Bs[2][NJ * 64][64];
  const int tid = threadIdx.x;
  const int l   = tid & 63;
  const int wid = tid >> 6;
  const int wm  = wid >> 2;
  const int wn  = wid & 3;

  const int nwg = gridDim.x;
  const int cpx = nwg >> 3;
  const int bid = blockIdx.x;
  const int wg  = (bid & 7) * cpx + (bid >> 3);
  const int by  = wg / gx;
  const int bx  = wg - by * gx;
  const int m0  = bx * 128;
  const int n0  = by * (NJ * 64);

  f32x4 acc[4][NJ] = {};
  const int lr = l >> 3;
  const int lc = ((l & 7) ^ lr) * 8;
  const int ca = wid * CH;

  auto STAGE = [&](int buf, int k0) {
#pragma unroll
    for (int i = 0; i < CH; ++i) {
      int c = ca + i;
      if (c < 16) {
        const u16* src = A + (size_t)(m0 + c * 8 + lr) * DIN + k0 + lc;
        __builtin_amdgcn_global_load_lds(
            (const __attribute__((address_space(1))) unsigned int*)src,
            (__attribute__((address_space(3))) unsigned int*)&As[buf][c * 8][0],
            16, 0, 0);
      } else {
        int cb = c - 16;
        const u16* src = BT + (size_t)(n0 + cb * 8 + lr) * DIN + k0 + lc;
        __builtin_amdgcn_global_load_lds(
            (const __attribute__((address_space(1))) unsigned int*)src,
            (__attribute__((address_space(3))) unsigned int*)&Bs[buf][cb * 8][0],
            16, 0, 0);
      }
    }
  };

  STAGE(0, 0);
  __syncthreads();
  int cur = 0;
  for (int k0 = 0; k0 < DIN; k0 += 64) {
    if (k0 + 64 < DIN) STAGE(cur ^ 1, k0 + 64);
#pragma unroll
    for (int ks = 0; ks < 2; ++ks) {
      short8 af[4], bg[NJ];
#pragma unroll
      for (int i = 0; i < 4; ++i) {
        int row  = wm * 64 + i * 16 + (l & 15);
        int slot = (ks * 4 + (l >> 4)) ^ (row & 7);
        af[i] = *(const short8*)&As[cur][row][slot * 8];
      }
#pragma unroll
      for (int j = 0; j < NJ; ++j) {
        int row  = wn * (NJ * 16) + j * 16 + (l & 15);
        int slot = (ks * 4 + (l >> 4)) ^ (row & 7);
        bg[j] = *(const short8*)&Bs[cur][row][slot * 8];
      }
#pragma unroll
      for (int i = 0; i < 4; ++i)
#pragma unroll
        for (int j = 0; j < NJ; ++j)
          acc[i][j] = __builtin_amdgcn_mfma_f32_16x16x32_bf16(af[i], bg[j], acc[i][j], 0, 0, 0);
    }
    __syncthreads();
    cur ^= 1;
  }

  const int rbase = (l >> 4) * 4;
  const int cl    = l & 15;
#pragma unroll
  for (int i = 0; i < 4; ++i) {
#pragma unroll
    for (int j = 0; j < NJ; ++j) {
      int col = n0 + wn * (NJ * 16) + j * 16 + cl;
      int row0 = m0 + wm * 64 + i * 16 + rbase;
      float bv_ = bias[col];
      if (n0 < 256) {
#pragma unroll
        for (int q = 0; q < 4; ++q)
          C0[(size_t)(row0 + q) * 256 + col] = f2bf(acc[i][j][q] + bv_);
      } else {
        int b = row0 >> 11, t = row0 & 2047;
        u16 o[4];
#pragma unroll
        for (int q = 0; q < 4; ++q) o[q] = f2bf(acc[i][j][q] + bv_);
        *(uint2*)&C1[((size_t)b * DV + (col - 256)) * SEQ + t] = *(const uint2*)o;
      }
    }
  }
}

// ---------------- PV GEMM: 3-buffer counted-vmcnt pipeline ----------------
// out = (P @ vT^T) / rowsum(P); rowsum via ones-MFMA. 128x192 tile, 8 waves,
// 3 LDS buffers (120KB, 1 block/CU), prefetch distance 2, raw s_barrier +
// s_waitcnt vmcnt(5) (counted, never 0 mid-loop; CH=5 loads/wave/tile).
__global__ __launch_bounds__(512, 2) void gemm_pv(
    const u16* __restrict__ P, const u16* __restrict__ vT,
    float* __restrict__ out)
{
  const int NJ = 3, CH = 5, gx = 16, gy = 4, NT = SEQ / 64;  // 32 K-tiles
  __shared__ u16 As[3][128][64];       // 48 KB
  __shared__ u16 Bs[3][NJ * 64][64];   // 72 KB
  const int tid = threadIdx.x;
  const int l   = tid & 63;
  const int wid = tid >> 6;
  const int wm  = wid >> 2;
  const int wn  = wid & 3;

  const int nwg = gridDim.x;           // 256
  const int cpx = nwg >> 3;
  const int bid = blockIdx.x;
  const int wg  = (bid & 7) * cpx + (bid >> 3);
  const int z   = wg / (gx * gy);
  const int rem = wg - z * gx * gy;
  const int by  = rem / gx;
  const int bx  = rem - by * gx;
  const int m0  = bx * 128;
  const int n0  = by * (NJ * 64);

  const u16* A  = P  + (size_t)z * SEQ * SEQ;
  const u16* BT = vT + (size_t)z * DV * SEQ;

  f32x4 acc[4][NJ] = {};
  f32x4 accO[4] = {};
  const short8 kOnes = {16256,16256,16256,16256,16256,16256,16256,16256};

  const int lr = l >> 3;
  const int lc = ((l & 7) ^ lr) * 8;
  const int ca = wid * CH;

  auto STAGE = [&](int buf, int k0) {
#pragma unroll
    for (int i = 0; i < CH; ++i) {
      int c = ca + i;
      if (c < 16) {
        const u16* src = A + (size_t)(m0 + c * 8 + lr) * SEQ + k0 + lc;
        __builtin_amdgcn_global_load_lds(
            (const __attribute__((address_space(1))) unsigned int*)src,
            (__attribute__((address_space(3))) unsigned int*)&As[buf][c * 8][0],
            16, 0, 0);
      } else {
        int cb = c - 16;
        const u16* src = BT + (size_t)(n0 + cb * 8 + lr) * SEQ + k0 + lc;
        __builtin_amdgcn_global_load_lds(
            (const __attribute__((address_space(1))) unsigned int*)src,
            (__attribute__((address_space(3))) unsigned int*)&Bs[buf][cb * 8][0],
            16, 0, 0);
      }
    }
  };

  auto COMPUTE = [&](int buf) {
#pragma unroll
    for (int ks = 0; ks < 2; ++ks) {
      short8 af[4], bg[NJ];
#pragma unroll
      for (int i = 0; i < 4; ++i) {
        int row  = wm * 64 + i * 16 + (l & 15);
        int slot = (ks * 4 + (l >> 4)) ^ (row & 7);
        af[i] = *(const short8*)&As[buf][row][slot * 8];
      }
#pragma unroll
      for (int j = 0; j < NJ; ++j) {
        int row  = wn * (NJ * 16) + j * 16 + (l & 15);
        int slot = (ks * 4 + (l >> 4)) ^ (row & 7);
        bg[j] = *(const short8*)&Bs[buf][row][slot * 8];
      }
#pragma unroll
      for (int i = 0; i < 4; ++i)
#pragma unroll
        for (int j = 0; j < NJ; ++j)
          acc[i][j] = __builtin_amdgcn_mfma_f32_16x16x32_bf16(af[i], bg[j], acc[i][j], 0, 0, 0);
#pragma unroll
      for (int i = 0; i < 4; ++i)
        accO[i] = __builtin_amdgcn_mfma_f32_16x16x32_bf16(af[i], kOnes, accO[i], 0, 0, 0);
    }
  };

  STAGE(0, 0);
  STAGE(1, 64);
  int cur = 0;
  for (int t = 0; t < NT - 1; ++t) {
    wait_vmcnt<CH>();                  // tile t done; tile t+1 may be in flight
    __builtin_amdgcn_s_barrier();
    COMPUTE(cur);
    if (t + 2 < NT) STAGE(cur + 2 >= 3 ? cur - 1 : cur + 2, (t + 2) * 64);
    cur = (cur + 1 == 3) ? 0 : cur + 1;
  }
  wait_vmcnt<0>();
  __builtin_amdgcn_s_barrier();
  COMPUTE(cur);

  const int rbase = (l >> 4) * 4;
  const int cl    = l & 15;
#pragma unroll
  for (int i = 0; i < 4; ++i) {
    f32x4 rs;
#pragma unroll
    for (int q = 0; q < 4; ++q) rs[q] = 1.0f / accO[i][q];
#pragma unroll
    for (int j = 0; j < NJ; ++j) {
      int col  = n0 + wn * (NJ * 16) + j * 16 + cl;
      int row0 = m0 + wm * 64 + i * 16 + rbase;
#pragma unroll
      for (int q = 0; q < 4; ++q)
        out[(size_t)z * SEQ * DV + (size_t)(row0 + q) * DV + col] = acc[i][j][q] * rs[q];
    }
  }
}

// ---------------- K3: S-GEMM, K=128 single-stage: P = exp(q_s @ k^T), bf16 out ----------------
__global__ __launch_bounds__(512, 4) void sgemm_exp(
    const u16* __restrict__ qk, u16* __restrict__ P)
{
  __shared__ u16 As[128][128];
  __shared__ u16 Bs[128][128];
  const int tid = threadIdx.x;
  const int l   = tid & 63;
  const int wid = tid >> 6;
  const int wm  = wid >> 2;
  const int wn  = wid & 3;

  const int nwg = gridDim.x;      // 1024
  const int cpx = nwg >> 3;
  const int bid = blockIdx.x;
  const int wg  = (bid & 7) * cpx + (bid >> 3);
  const int z   = wg >> 8;
  const int rem = wg & 255;
  const int by  = rem >> 4;
  const int bx  = rem & 15;
  const int m0  = bx * 128;
  const int n0  = by * 128;

  const u16* A  = qk + (size_t)z * SEQ * 256;
  const u16* BT = qk + DK + (size_t)z * SEQ * 256;

  const int rin  = l >> 4;
  const int s16  = l & 15;
#pragma unroll
  for (int i = 0; i < 8; ++i) {
    int c = wid * 8 + i;
    if (c < 32) {
      int r = c * 4 + rin;
      int gs = s16 ^ (r & 7);
      const u16* src = A + (size_t)(m0 + r) * 256 + gs * 8;
      __builtin_amdgcn_global_load_lds(
          (const __attribute__((address_space(1))) unsigned int*)src,
          (__attribute__((address_space(3))) unsigned int*)&As[c * 4][0],
          16, 0, 0);
    } else {
      int cb = c - 32;
      int r = cb * 4 + rin;
      int gs = s16 ^ (r & 7);
      const u16* src = BT + (size_t)(n0 + r) * 256 + gs * 8;
      __builtin_amdgcn_global_load_lds(
          (const __attribute__((address_space(1))) unsigned int*)src,
          (__attribute__((address_space(3))) unsigned int*)&Bs[cb * 4][0],
          16, 0, 0);
    }
  }
  __syncthreads();

  f32x4 acc[4][2] = {};
#pragma unroll
  for (int ks = 0; ks < 4; ++ks) {
    short8 af[4], bg[2];
#pragma unroll
    for (int i = 0; i < 4; ++i) {
      int row  = wm * 64 + i * 16 + (l & 15);
      int slot = (ks * 4 + (l >> 4)) ^ (row & 7);
      af[i] = *(const short8*)&As[row][slot * 8];
    }
#pragma unroll
    for (int j = 0; j < 2; ++j) {
      int row  = wn * 32 + j * 16 + (l & 15);
      int slot = (ks * 4 + (l >> 4)) ^ (row & 7);
      bg[j] = *(const short8*)&Bs[row][slot * 8];
    }
#pragma unroll
    for (int i = 0; i < 4; ++i)
#pragma unroll
      for (int j = 0; j < 2; ++j)
        acc[i][j] = __builtin_amdgcn_mfma_f32_16x16x32_bf16(af[i], bg[j], acc[i][j], 0, 0, 0);
  }

  const int rbase = (l >> 4) * 4;
  const int cl    = l & 15;
  u16* Pz = P + (size_t)z * SEQ * SEQ;
#pragma unroll
  for (int i = 0; i < 4; ++i)
#pragma unroll
    for (int j = 0; j < 2; ++j) {
      int col  = n0 + wn * 32 + j * 16 + cl;
      int row0 = m0 + wm * 64 + i * 16 + rbase;
#pragma unroll
      for (int q = 0; q < 4; ++q)
        Pz[(size_t)(row0 + q) * SEQ + col] = f2bf(__expf(acc[i][j][q]));
    }
}

extern "C" void kernel_launch(void* const* d_in, const int* in_sizes, int n_in,
                              void* d_out, int out_size, void* d_ws, size_t ws_size,
                              hipStream_t stream) {
  const float* x  = (const float*)d_in[0];
  const float* Wq = (const float*)d_in[1];
  const float* bq = (const float*)d_in[2];
  const float* Wk = (const float*)d_in[3];
  const float* bk = (const float*)d_in[4];
  const float* Wv = (const float*)d_in[5];
  const float* bv = (const float*)d_in[6];
  float* out = (float*)d_out;

  size_t off = 0;
  auto alloc = [&](size_t bytes) -> void* {
    void* p = (char*)d_ws + off;
    off += (bytes + 255) & ~(size_t)255;
    return p;
  };
  u16*   xb    = (u16*)alloc((size_t)MTOT * DIN * 2);
  u16*   WbT   = (u16*)alloc((size_t)NQKV * DIN * 2);
  float* biasP = (float*)alloc(NQKV * 4);
  u16*   qk    = (u16*)alloc((size_t)MTOT * 256 * 2);
  u16*   vT    = (u16*)alloc((size_t)BATCH * DV * SEQ * 2);
  u16*   P     = (u16*)alloc((size_t)BATCH * SEQ * SEQ * 2);
  if (off > ws_size) return;

  pack_all<<<dim3(DIN/64, 16), dim3(256), 0, stream>>>(Wq, bq, Wk, bk, Wv, bv, WbT, biasP);
  convert_x<<<dim3((MTOT * DIN / 4) / 256), dim3(256), 0, stream>>>(x, xb);

  // proj: [8192,1024] = xb @ WbT^T + bias; writes qk (n<256) and vT (transposed)
  gemm_proj<<<dim3(64 * 8), dim3(512), 0, stream>>>(xb, WbT, qk, vT, biasP);

  // P = exp(q_scaled @ k^T) per batch (M=N=2048, K=128), single-stage
  sgemm_exp<<<dim3(16 * 16 * BATCH), dim3(512), 0, stream>>>(qk, P);

  // out = (P @ vT^T) / rowsum(P) per batch, 3-buffer counted-vmcnt pipeline
  gemm_pv<<<dim3(16 * 4 * BATCH), dim3(512), 0, stream>>>(P, vT, out);
}

// Round 8
// 84.447 us; speedup vs baseline: 1.4379x; 1.0127x over previous
//
#include <hip/hip_runtime.h>
#include <stdint.h>

typedef unsigned short u16;
typedef __attribute__((ext_vector_type(8))) short short8;
typedef __attribute__((ext_vector_type(4))) float f32x4;

#define BATCH 4
#define SEQ   2048
#define DIN   768
#define DK    128
#define DV    768
#define MTOT  (BATCH*SEQ)   // 8192
#define NQKV  1024          // 128 q + 128 k + 768 v

__device__ __forceinline__ u16 f2bf(float f) {
  union { float f; uint32_t u; } v; v.f = f;
  uint32_t r = v.u + 0x7FFFu + ((v.u >> 16) & 1u);
  return (u16)(r >> 16);
}

template<int N> __device__ __forceinline__ void wait_vmcnt() {
  if constexpr (N == 0) asm volatile("s_waitcnt vmcnt(0)" ::: "memory");
  else if constexpr (N == 5) asm volatile("s_waitcnt vmcnt(5)" ::: "memory");
  else if constexpr (N == 10) asm volatile("s_waitcnt vmcnt(10)" ::: "memory");
}

// ---------------- K0: prep = convert_x (blocks < 6144) + pack weights/bias ----------------
__global__ __launch_bounds__(256) void prep(
    const float* __restrict__ x, u16* __restrict__ xb,
    const float* __restrict__ Wq, const float* __restrict__ bq,
    const float* __restrict__ Wk, const float* __restrict__ bk,
    const float* __restrict__ Wv, const float* __restrict__ bv,
    u16* __restrict__ WbT, float* __restrict__ biasP) {
  const float qs = 0.088388347648318447f;  // 1/sqrt(128)
  __shared__ u16 tile[64][72];
  int b = blockIdx.x;
  int tid = threadIdx.x;
  if (b < 6144) {               // convert x -> bf16
    int i = (b * 256 + tid) * 4;
    float4 v = *(const float4*)(x + i);
    u16 o[4] = { f2bf(v.x), f2bf(v.y), f2bf(v.z), f2bf(v.w) };
    *(uint2*)(xb + i) = *(const uint2*)o;
    return;
  }
  int bid2 = b - 6144;          // 0..191 : pack weights (12 x 16)
  int y   = bid2 / 12;
  int i0  = (bid2 - y * 12) * 64;
  const float* W; u16* dst; int ldw, nb; float sc;
  if (y < 2)      { W = Wq; dst = WbT;                      ldw = DK; sc = qs;   nb = y;     }
  else if (y < 4) { W = Wk; dst = WbT + (size_t)DK * DIN;   ldw = DK; sc = 1.0f; nb = y - 2; }
  else            { W = Wv; dst = WbT + (size_t)2*DK * DIN; ldw = DV; sc = 1.0f; nb = y - 4; }
  int n0 = nb * 64;
  if (i0 == 0 && y == 0) {
    for (int n = tid; n < NQKV; n += 256)
      biasP[n] = (n < DK) ? bq[n] * qs : (n < 2*DK ? bk[n - DK] : bv[n - 2*DK]);
  }
  int tr = tid >> 2;
  int tc = (tid & 3) * 16;
  const float* src = W + (size_t)(i0 + tr) * ldw + n0 + tc;
  u16 o[16];
#pragma unroll
  for (int u = 0; u < 16; u += 4) {
    float4 v = *(const float4*)(src + u);
    o[u] = f2bf(v.x * sc); o[u+1] = f2bf(v.y * sc); o[u+2] = f2bf(v.z * sc); o[u+3] = f2bf(v.w * sc);
  }
  *(uint4*)&tile[tr][tc]     = *(const uint4*)&o[0];
  *(uint4*)&tile[tr][tc + 8] = *(const uint4*)&o[8];
  __syncthreads();
  u16 tmp[16];
#pragma unroll
  for (int u = 0; u < 16; ++u) tmp[u] = tile[tc + u][tr];
  u16* d = dst + (size_t)(n0 + tr) * DIN + i0 + tc;
  *(uint4*)d       = *(const uint4*)&tmp[0];
  *(uint4*)(d + 8) = *(const uint4*)&tmp[8];
}

// ---------------- proj GEMM (2-phase dbuf): qkv projection ----------------
// n0<256 -> C0=qk bf16 [M][256]; n0>=256 -> C1=vT bf16 [BATCH][DV][SEQ] TRANSPOSED.
__global__ __launch_bounds__(512, 4) void gemm_proj(
    const u16* __restrict__ A, const u16* __restrict__ BT,
    u16* __restrict__ C0, u16* __restrict__ C1,
    const float* __restrict__ bias)
{
  const int NJ = 2, CH = 4, gx = 64;
  __shared__ u16 As[2][128][64];
  __shared__ u16 Bs[2][NJ * 64][64];
  const int tid = threadIdx.x;
  const int l   = tid & 63;
  const int wid = tid >> 6;
  const int wm  = wid >> 2;
  const int wn  = wid & 3;

  const int nwg = gridDim.x;
  const int cpx = nwg >> 3;
  const int bid = blockIdx.x;
  const int wg  = (bid & 7) * cpx + (bid >> 3);
  const int by  = wg / gx;
  const int bx  = wg - by * gx;
  const int m0  = bx * 128;
  const int n0  = by * (NJ * 64);

  f32x4 acc[4][NJ] = {};
  const int lr = l >> 3;
  const int lc = ((l & 7) ^ lr) * 8;
  const int ca = wid * CH;

  auto STAGE = [&](int buf, int k0) {
#pragma unroll
    for (int i = 0; i < CH; ++i) {
      int c = ca + i;
      if (c < 16) {
        const u16* src = A + (size_t)(m0 + c * 8 + lr) * DIN + k0 + lc;
        __builtin_amdgcn_global_load_lds(
            (const __attribute__((address_space(1))) unsigned int*)src,
            (__attribute__((address_space(3))) unsigned int*)&As[buf][c * 8][0],
            16, 0, 0);
      } else {
        int cb = c - 16;
        const u16* src = BT + (size_t)(n0 + cb * 8 + lr) * DIN + k0 + lc;
        __builtin_amdgcn_global_load_lds(
            (const __attribute__((address_space(1))) unsigned int*)src,
            (__attribute__((address_space(3))) unsigned int*)&Bs[buf][cb * 8][0],
            16, 0, 0);
      }
    }
  };

  STAGE(0, 0);
  __syncthreads();
  int cur = 0;
  for (int k0 = 0; k0 < DIN; k0 += 64) {
    if (k0 + 64 < DIN) STAGE(cur ^ 1, k0 + 64);
#pragma unroll
    for (int ks = 0; ks < 2; ++ks) {
      short8 af[4], bg[NJ];
#pragma unroll
      for (int i = 0; i < 4; ++i) {
        int row  = wm * 64 + i * 16 + (l & 15);
        int slot = (ks * 4 + (l >> 4)) ^ (row & 7);
        af[i] = *(const short8*)&As[cur][row][slot * 8];
      }
#pragma unroll
      for (int j = 0; j < NJ; ++j) {
        int row  = wn * (NJ * 16) + j * 16 + (l & 15);
        int slot = (ks * 4 + (l >> 4)) ^ (row & 7);
        bg[j] = *(const short8*)&Bs[cur][row][slot * 8];
      }
#pragma unroll
      for (int i = 0; i < 4; ++i)
#pragma unroll
        for (int j = 0; j < NJ; ++j)
          acc[i][j] = __builtin_amdgcn_mfma_f32_16x16x32_bf16(af[i], bg[j], acc[i][j], 0, 0, 0);
    }
    __syncthreads();
    cur ^= 1;
  }

  const int rbase = (l >> 4) * 4;
  const int cl    = l & 15;
#pragma unroll
  for (int i = 0; i < 4; ++i) {
#pragma unroll
    for (int j = 0; j < NJ; ++j) {
      int col = n0 + wn * (NJ * 16) + j * 16 + cl;
      int row0 = m0 + wm * 64 + i * 16 + rbase;
      float bv_ = bias[col];
      if (n0 < 256) {
#pragma unroll
        for (int q = 0; q < 4; ++q)
          C0[(size_t)(row0 + q) * 256 + col] = f2bf(acc[i][j][q] + bv_);
      } else {
        int b = row0 >> 11, t = row0 & 2047;
        u16 o[4];
#pragma unroll
        for (int q = 0; q < 4; ++q) o[q] = f2bf(acc[i][j][q] + bv_);
        *(uint2*)&C1[((size_t)b * DV + (col - 256)) * SEQ + t] = *(const uint2*)o;
      }
    }
  }
}

// ---------------- PV GEMM: 3-slot ring, depth-2 counted vmcnt, fine phases + setprio ----------------
// out = (P @ vT^T) / rowsum(P); rowsum via ones-MFMA. 128x192 tile, 8 waves.
// Per K-tile: wait vmcnt(5); barrier; 2 phases of {7 ds_read ; STAGE-half(t+2) ;
// setprio(1) 16 MFMA setprio(0)}.
__global__ __launch_bounds__(512, 2) void gemm_pv(
    const u16* __restrict__ P, const u16* __restrict__ vT,
    float* __restrict__ out)
{
  const int NJ = 3, CH = 5, gx = 16, gy = 4, NT = SEQ / 64;  // 32 K-tiles
  __shared__ u16 As[3][128][64];       // 48 KB
  __shared__ u16 Bs[3][NJ * 64][64];   // 72 KB
  const int tid = threadIdx.x;
  const int l   = tid & 63;
  const int wid = tid >> 6;
  const int wm  = wid >> 2;
  const int wn  = wid & 3;

  const int nwg = gridDim.x;           // 256
  const int cpx = nwg >> 3;
  const int bid = blockIdx.x;
  const int wg  = (bid & 7) * cpx + (bid >> 3);
  const int z   = wg / (gx * gy);
  const int rem = wg - z * gx * gy;
  const int by  = rem / gx;
  const int bx  = rem - by * gx;
  const int m0  = bx * 128;
  const int n0  = by * (NJ * 64);

  const u16* A  = P  + (size_t)z * SEQ * SEQ;
  const u16* BT = vT + (size_t)z * DV * SEQ;

  f32x4 acc[4][NJ] = {};
  f32x4 accO[4] = {};
  const short8 kOnes = {16256,16256,16256,16256,16256,16256,16256,16256};

  const int lr = l >> 3;
  const int lc = ((l & 7) ^ lr) * 8;
  const int ca = wid * CH;

  // STAGE chunks [i0,i1) of tile at k0 into slot buf
  auto STAGE = [&](int buf, int k0, int i0, int i1) {
#pragma unroll
    for (int i = 0; i < CH; ++i) {
      if (i < i0 || i >= i1) continue;
      int c = ca + i;
      if (c < 16) {
        const u16* src = A + (size_t)(m0 + c * 8 + lr) * SEQ + k0 + lc;
        __builtin_amdgcn_global_load_lds(
            (const __attribute__((address_space(1))) unsigned int*)src,
            (__attribute__((address_space(3))) unsigned int*)&As[buf][c * 8][0],
            16, 0, 0);
      } else {
        int cb = c - 16;
        const u16* src = BT + (size_t)(n0 + cb * 8 + lr) * SEQ + k0 + lc;
        __builtin_amdgcn_global_load_lds(
            (const __attribute__((address_space(1))) unsigned int*)src,
            (__attribute__((address_space(3))) unsigned int*)&Bs[buf][cb * 8][0],
            16, 0, 0);
      }
    }
  };

  STAGE(0, 0, 0, CH);
  STAGE(1, 64, 0, CH);
  int cur = 0;
  for (int t = 0; t < NT; ++t) {
    if (t == NT - 1) wait_vmcnt<0>(); else wait_vmcnt<CH>();
    __builtin_amdgcn_s_barrier();
    const int nxt2 = (cur + 2 >= 3) ? cur - 1 : cur + 2;
    const bool pf = (t + 2 < NT);
#pragma unroll
    for (int ks = 0; ks < 2; ++ks) {
      short8 af[4], bg[NJ];
#pragma unroll
      for (int i = 0; i < 4; ++i) {
        int row  = wm * 64 + i * 16 + (l & 15);
        int slot = (ks * 4 + (l >> 4)) ^ (row & 7);
        af[i] = *(const short8*)&As[cur][row][slot * 8];
      }
#pragma unroll
      for (int j = 0; j < NJ; ++j) {
        int row  = wn * (NJ * 16) + j * 16 + (l & 15);
        int slot = (ks * 4 + (l >> 4)) ^ (row & 7);
        bg[j] = *(const short8*)&Bs[cur][row][slot * 8];
      }
      if (pf) {
        if (ks == 0) STAGE(nxt2, (t + 2) * 64, 0, 3);
        else         STAGE(nxt2, (t + 2) * 64, 3, CH);
      }
      __builtin_amdgcn_s_setprio(1);
#pragma unroll
      for (int i = 0; i < 4; ++i) {
#pragma unroll
        for (int j = 0; j < NJ; ++j)
          acc[i][j] = __builtin_amdgcn_mfma_f32_16x16x32_bf16(af[i], bg[j], acc[i][j], 0, 0, 0);
        accO[i] = __builtin_amdgcn_mfma_f32_16x16x32_bf16(af[i], kOnes, accO[i], 0, 0, 0);
      }
      __builtin_amdgcn_s_setprio(0);
    }
    cur = (cur + 1 == 3) ? 0 : cur + 1;
  }

  const int rbase = (l >> 4) * 4;
  const int cl    = l & 15;
#pragma unroll
  for (int i = 0; i < 4; ++i) {
    f32x4 rs;
#pragma unroll
    for (int q = 0; q < 4; ++q) rs[q] = 1.0f / accO[i][q];
#pragma unroll
    for (int j = 0; j < NJ; ++j) {
      int col  = n0 + wn * (NJ * 16) + j * 16 + cl;
      int row0 = m0 + wm * 64 + i * 16 + rbase;
#pragma unroll
      for (int q = 0; q < 4; ++q)
        out[(size_t)z * SEQ * DV + (size_t)(row0 + q) * DV + col] = acc[i][j][q] * rs[q];
    }
  }
}

// ---------------- K3: S-GEMM, K=128 single-stage: P = exp(q_s @ k^T), bf16 out ----------------
__global__ __launch_bounds__(512, 4) void sgemm_exp(
    const u16* __restrict__ qk, u16* __restrict__ P)
{
  __shared__ u16 As[128][128];
  __shared__ u16 Bs[128][128];
  const int tid = threadIdx.x;
  const int l   = tid & 63;
  const int wid = tid >> 6;
  const int wm  = wid >> 2;
  const int wn  = wid & 3;

  const int nwg = gridDim.x;      // 1024
  const int cpx = nwg >> 3;
  const int bid = blockIdx.x;
  const int wg  = (bid & 7) * cpx + (bid >> 3);
  const int z   = wg >> 8;
  const int rem = wg & 255;
  const int by  = rem >> 4;
  const int bx  = rem & 15;
  const int m0  = bx * 128;
  const int n0  = by * 128;

  const u16* A  = qk + (size_t)z * SEQ * 256;
  const u16* BT = qk + DK + (size_t)z * SEQ * 256;

  const int rin  = l >> 4;
  const int s16  = l & 15;
#pragma unroll
  for (int i = 0; i < 8; ++i) {
    int c = wid * 8 + i;
    if (c < 32) {
      int r = c * 4 + rin;
      int gs = s16 ^ (r & 7);
      const u16* src = A + (size_t)(m0 + r) * 256 + gs * 8;
      __builtin_amdgcn_global_load_lds(
          (const __attribute__((address_space(1))) unsigned int*)src,
          (__attribute__((address_space(3))) unsigned int*)&As[c * 4][0],
          16, 0, 0);
    } else {
      int cb = c - 32;
      int r = cb * 4 + rin;
      int gs = s16 ^ (r & 7);
      const u16* src = BT + (size_t)(n0 + r) * 256 + gs * 8;
      __builtin_amdgcn_global_load_lds(
          (const __attribute__((address_space(1))) unsigned int*)src,
          (__attribute__((address_space(3))) unsigned int*)&Bs[cb * 4][0],
          16, 0, 0);
    }
  }
  __syncthreads();

  f32x4 acc[4][2] = {};
#pragma unroll
  for (int ks = 0; ks < 4; ++ks) {
    short8 af[4], bg[2];
#pragma unroll
    for (int i = 0; i < 4; ++i) {
      int row  = wm * 64 + i * 16 + (l & 15);
      int slot = (ks * 4 + (l >> 4)) ^ (row & 7);
      af[i] = *(const short8*)&As[row][slot * 8];
    }
#pragma unroll
    for (int j = 0; j < 2; ++j) {
      int row  = wn * 32 + j * 16 + (l & 15);
      int slot = (ks * 4 + (l >> 4)) ^ (row & 7);
      bg[j] = *(const short8*)&Bs[row][slot * 8];
    }
#pragma unroll
    for (int i = 0; i < 4; ++i)
#pragma unroll
      for (int j = 0; j < 2; ++j)
        acc[i][j] = __builtin_amdgcn_mfma_f32_16x16x32_bf16(af[i], bg[j], acc[i][j], 0, 0, 0);
  }

  const int rbase = (l >> 4) * 4;
  const int cl    = l & 15;
  u16* Pz = P + (size_t)z * SEQ * SEQ;
#pragma unroll
  for (int i = 0; i < 4; ++i)
#pragma unroll
    for (int j = 0; j < 2; ++j) {
      int col  = n0 + wn * 32 + j * 16 + cl;
      int row0 = m0 + wm * 64 + i * 16 + rbase;
#pragma unroll
      for (int q = 0; q < 4; ++q)
        Pz[(size_t)(row0 + q) * SEQ + col] = f2bf(__expf(acc[i][j][q]));
    }
}

extern "C" void kernel_launch(void* const* d_in, const int* in_sizes, int n_in,
                              void* d_out, int out_size, void* d_ws, size_t ws_size,
                              hipStream_t stream) {
  const float* x  = (const float*)d_in[0];
  const float* Wq = (const float*)d_in[1];
  const float* bq = (const float*)d_in[2];
  const float* Wk = (const float*)d_in[3];
  const float* bk = (const float*)d_in[4];
  const float* Wv = (const float*)d_in[5];
  const float* bv = (const float*)d_in[6];
  float* out = (float*)d_out;

  size_t off = 0;
  auto alloc = [&](size_t bytes) -> void* {
    void* p = (char*)d_ws + off;
    off += (bytes + 255) & ~(size_t)255;
    return p;
  };
  u16*   xb    = (u16*)alloc((size_t)MTOT * DIN * 2);
  u16*   WbT   = (u16*)alloc((size_t)NQKV * DIN * 2);
  float* biasP = (float*)alloc(NQKV * 4);
  u16*   qk    = (u16*)alloc((size_t)MTOT * 256 * 2);
  u16*   vT    = (u16*)alloc((size_t)BATCH * DV * SEQ * 2);
  u16*   P     = (u16*)alloc((size_t)BATCH * SEQ * SEQ * 2);
  if (off > ws_size) return;

  prep<<<dim3(6144 + 192), dim3(256), 0, stream>>>(x, xb, Wq, bq, Wk, bk, Wv, bv, WbT, biasP);

  // proj: [8192,1024] = xb @ WbT^T + bias; writes qk (n<256) and vT (transposed)
  gemm_proj<<<dim3(64 * 8), dim3(512), 0, stream>>>(xb, WbT, qk, vT, biasP);

  // P = exp(q_scaled @ k^T) per batch (M=N=2048, K=128), single-stage
  sgemm_exp<<<dim3(16 * 16 * BATCH), dim3(512), 0, stream>>>(qk, P);

  // out = (P @ vT^T) / rowsum(P) per batch, fine-phase pipelined
  gemm_pv<<<dim3(16 * 4 * BATCH), dim3(512), 0, stream>>>(P, vT, out);
}